// Round 11
// baseline (18442.929 us; speedup 1.0000x reference)
//
#include <hip/hip_runtime.h>

// ---------------------------------------------------------------------------
// 2-layer LSTM encoder, B=128 T=512 E=256 H=1024 (round 11).
// Persistent kernel: 256 blocks x 1024 threads (16 waves, 4/SIMD).
// Layer-specialized waves: 0-7 -> L0 rows w*16 (40 kt), 8-15 -> L1 (64 kt).
// Per phase p: L0 (t=p): z0=[x_p;h0(p-1)]@W0 -> h0(p)
//             L1 (t=p-1): z1=[h0(p-1);h1(p-2)]@W1 -> h1(p-1)
// Split-bf16 x3 MFMA (verified r1-r10). W-hi LDS-resident (W1 kt52..63
// streamed inside chunks C3/C4). W-lo staged via async global_load_lds in
// 5 big chunks (dbuf, stage-1-ahead). LLC (sc0 sc1) flag barriers (r10).
// r11: 2x TLP (4 waves/SIMD) for the measured latency-bound regime; per-wave
// chunk bodies halved; cells parallel across halves; dist on tid<512.
// ---------------------------------------------------------------------------

namespace {
constexpr int NBLK = 256, THREADS = 1024;
constexpr int KT0B = 40;           // L0 k-tiles of 32 (K=1280): 8 X + 32 D
constexpr int KT1B = 64;           // L1 k-tiles of 32 (K=2048): 32 D + 32 H1
constexpr int WH1KT = 52;          // W1-hi kt resident in LDS (52..63 streamed)
constexpr int NPH = 513;
constexpr int HP = 128 * 1024;     // u16 elems per h plane
constexpr int SPIN_CAP = 2000000;
// flag slots (u32 index into ctr, zeroed per launch) — ALL LLC (r10-proven)
constexpr int F_CREG = 0;          // 8 x 16 (boot atomics)
constexpr int F_BOOT = 128;
constexpr int F_ARR  = 256;        // 256 contiguous (global arrive)
constexpr int F_GO   = 520;
constexpr int F_XARR = 576;        // 8 x 64 (mid-phase XCD arrive)
constexpr int kNSLAB[5] = {24, 24, 24, 20, 24};
}

typedef __bf16 bf16x8 __attribute__((ext_vector_type(8)));
typedef float f32x4 __attribute__((ext_vector_type(4)));
typedef unsigned u32x4 __attribute__((ext_vector_type(4)));

__host__ __device__ __forceinline__ int fswz(int kk) {   // frag order within 32
  return ((kk & 15) >> 2) * 8 + (kk >> 4) * 4 + (kk & 3);
}

__device__ __forceinline__ unsigned short f2bf(float f) {
  unsigned u = __float_as_uint(f);
  u += 0x7fffu + ((u >> 16) & 1u);
  return (unsigned short)(u >> 16);
}
__device__ __forceinline__ float bf2f(unsigned short h) {
  return __uint_as_float(((unsigned)h) << 16);
}
__device__ __forceinline__ float sigm(float x) { return 1.0f / (1.0f + __expf(-x)); }
__device__ __forceinline__ float tanh_f(float x) {
  float e = __expf(-2.0f * fabsf(x));
  float r = (1.0f - e) / (1.0f + e);
  return x >= 0.0f ? r : -r;
}

// ---- LLC-coherent ops (bypass L1+L2) --------------------------------------
__device__ __forceinline__ int load_i32_llc(const int* p) {
  int v;
  asm volatile("global_load_dword %0, %1, off sc0 sc1\n\ts_waitcnt vmcnt(0)"
               : "=v"(v) : "v"(p) : "memory");
  return v;
}
__device__ __forceinline__ uint4 llc_load_issue(const unsigned* p) {
  uint4 v;
  asm volatile("global_load_dwordx4 %0, %1, off sc0 sc1" : "=v"(v) : "v"(p));
  return v;
}
__device__ __forceinline__ void vm_wait0() {
  asm volatile("s_waitcnt vmcnt(0)" ::: "memory");
  __builtin_amdgcn_sched_barrier(0);
}
__device__ __forceinline__ void store_u32_llc(unsigned* p, unsigned v) {
  asm volatile("global_store_dword %0, %1, off sc0 sc1" :: "v"(p), "v"(v) : "memory");
}
__device__ __forceinline__ void store_u16_llc(unsigned short* p, unsigned short v) {
  asm volatile("global_store_short %0, %1, off sc0 sc1" :: "v"(p), "v"(v) : "memory");
}
__device__ __forceinline__ void inv_l1() {
  asm volatile("buffer_inv" ::: "memory");
}
__device__ __forceinline__ int xcc_id() {
  int x;
  asm("s_getreg_b32 %0, hwreg(HW_REG_XCC_ID)" : "=s"(x));
  return x & 7;
}
__device__ __forceinline__ int spin_ge(int* p, int target) {
  for (int it = 0; it < SPIN_CAP; ++it) {
    if (load_i32_llc(p) >= target) return 1;
    __builtin_amdgcn_s_sleep(1);
  }
  return 0;
}
__device__ __forceinline__ bf16x8 asbf(u32x4 v) { return __builtin_bit_cast(bf16x8, v); }
__device__ __forceinline__ bf16x8 asbf4(uint4 v) { return __builtin_bit_cast(bf16x8, v); }

// async global -> LDS, 16B per lane (dest = wave-uniform base + lane*16)
typedef __attribute__((address_space(1))) void gas_void;
typedef __attribute__((address_space(3))) void las_void;
__device__ __forceinline__ void gll16(const void* g, void* l) {
  __builtin_amdgcn_global_load_lds((gas_void*)g, (las_void*)l, 16, 0, 0);
}

#define MFMA3(acc, ah, al, bh, bl)                                            \
  acc = __builtin_amdgcn_mfma_f32_16x16x32_bf16(ah, bh, acc, 0, 0, 0);        \
  acc = __builtin_amdgcn_mfma_f32_16x16x32_bf16(ah, bl, acc, 0, 0, 0);        \
  acc = __builtin_amdgcn_mfma_f32_16x16x32_bf16(al, bh, acc, 0, 0, 0);

// ======================= prep kernels =====================================

__global__ void prep_sort(const int* __restrict__ lens, int* __restrict__ perm,
                          int* __restrict__ lenS, int* __restrict__ ncnt) {
  __shared__ int k_[128], p_[128];
  const int tid = threadIdx.x;
  if (tid < 128) { k_[tid] = (lens[tid] << 8) | (127 - tid); p_[tid] = tid; }
  __syncthreads();
  for (int ph = 0; ph < 128; ++ph) {
    if (tid < 64) {
      int a = 2 * tid + (ph & 1), b = a + 1;
      if (b < 128 && k_[a] < k_[b]) {
        int tk = k_[a]; k_[a] = k_[b]; k_[b] = tk;
        int tp = p_[a]; p_[a] = p_[b]; p_[b] = tp;
      }
    }
    __syncthreads();
  }
  if (tid < 128) { perm[tid] = p_[tid]; lenS[tid] = k_[tid] >> 8; }
  if (tid < 512) {
    int c = 0;
    for (int i = 0; i < 128; ++i) c += ((k_[i] >> 8) > tid) ? 1 : 0;
    ncnt[tid] = c;
  }
}

__global__ void prep_emb(const float* __restrict__ emb,
                         unsigned short* __restrict__ ehi,
                         unsigned short* __restrict__ elo) {
  int i = blockIdx.x * 256 + threadIdx.x;   // 32768
  int row = i >> 8, e = i & 255;
  int pos = row * 256 + (e >> 5) * 32 + fswz(e & 31);
  float f = emb[i];
  unsigned short h = f2bf(f);
  ehi[pos] = h;
  elo[pos] = f2bf(f - bf2f(h));
}

// W[k][4096] -> per-block frag slabs: e = (blk*KT + kt)*64 + lane.
__global__ void prep_wslab(const float* __restrict__ W, uint4* __restrict__ Whi,
                           uint4* __restrict__ Wlo, int KT) {
  int e = blockIdx.x * 256 + threadIdx.x;
  int lane = e & 63;
  int kt = (e >> 6) % KT;
  int blk = e / (64 * KT);
  int cf = lane & 15;
  int g = cf & 3, ul = cf >> 2;
  int col = g * 1024 + blk * 4 + ul;
  int kbase = kt * 32 + ((lane >> 4) & 3) * 4;
  unsigned hi[8], lo[8];
#pragma unroll
  for (int j = 0; j < 8; ++j) {
    int k = kbase + (j & 3) + 16 * (j >> 2);
    float f = W[(size_t)k * 4096 + col];
    unsigned short h = f2bf(f);
    hi[j] = h;
    lo[j] = f2bf(f - bf2f(h));
  }
  uint4 vh, vl;
  vh.x = hi[0] | (hi[1] << 16); vh.y = hi[2] | (hi[3] << 16);
  vh.z = hi[4] | (hi[5] << 16); vh.w = hi[6] | (hi[7] << 16);
  vl.x = lo[0] | (lo[1] << 16); vl.y = lo[2] | (lo[3] << 16);
  vl.z = lo[4] | (lo[5] << 16); vl.w = lo[6] | (lo[7] << 16);
  Whi[e] = vh;
  Wlo[e] = vl;
}

// ======================= persistent kernel =================================

__global__ __launch_bounds__(THREADS, 1) void lstm_persist(
    const int* __restrict__ ib,
    const float* __restrict__ bias0, const float* __restrict__ bias1,
    const uint4* __restrict__ Whi0g, const uint4* __restrict__ Wlo0g,
    const uint4* __restrict__ Whi1g, const uint4* __restrict__ Wlo1g,
    const unsigned short* __restrict__ embHi, const unsigned short* __restrict__ embLo,
    const int* __restrict__ perm, const int* __restrict__ lenS,
    const int* __restrict__ ncnt,
    unsigned short* hg0hi, unsigned short* hg0lo,   // [3][128][1024] frag-order
    unsigned short* hg1hi, unsigned short* hg1lo,
    unsigned short* rep,                            // [8][4][128][1024]
    int* ctr, float* __restrict__ out) {
  const int bid = blockIdx.x;
  const int tid = threadIdx.x;
  const int w = tid >> 6;                 // wave 0..15
  const bool isL0 = (w < 8);
  const int wl = w & 7;                   // layer-local wave -> rows wl*16..+15
  const int lane = tid & 63;
  const int lr = lane & 15;
  const int lg4 = ((lane >> 4) & 3) * 4;
  const int slotE = ((lane >> 4) & 3) * 8;  // frag u16 offset within 32-group
  const int arow = wl * 16 + lr;          // GEMM A row for this lane
  const int srow = (tid & 511) >> 2;      // cell row 0..127 (per half)
  const int cu = tid & 3;                 // cell unit 0..3
  const int ug = bid * 4 + cu;            // global unit
  const int fpos = (ug >> 5) * 32 + fswz(ug & 31);
  const int permA = perm[arow];
  const int cperm = perm[srow];
  const int clen = lenS[srow];

  __shared__ uint4 Wh0[KT0B * 64];              // 40 KB
  __shared__ uint4 Wh1[WH1KT * 64];             // 52 KB
  __shared__ __align__(16) u32x4 Wch[2][24 * 64];  // 48 KB (2 x 24KB chunks)
  __shared__ float zb[2][128][17];              // 17 KB
  __shared__ int s_x, s_rk, s_R, s_ok;

  // ---- one-time: W-hi slabs -> LDS ----
  {
    const uint4* s0 = Whi0g + (size_t)bid * (KT0B * 64);
    for (int i = tid; i < KT0B * 64; i += THREADS) Wh0[i] = s0[i];
    const uint4* s1 = Whi1g + (size_t)bid * (KT1B * 64);
    for (int i = tid; i < WH1KT * 64; i += THREADS) Wh1[i] = s1[i];
  }

  float bz[4];
#pragma unroll
  for (int g = 0; g < 4; ++g)
    bz[g] = (isL0 ? bias0 : bias1)[g * 1024 + ug];
  float cr = 0.0f;                        // cell state (c0 lower half, c1 upper)

  // ---- bootstrap (LLC atomics, once) ----
  if (tid == 0) {
    s_ok = 1;
    int x = xcc_id();
    s_x = x;
    s_rk = atomicAdd(&ctr[F_CREG + x * 16], 1);
    vm_wait0();
    atomicAdd(&ctr[F_BOOT], 1);
    if (!spin_ge(&ctr[F_BOOT], NBLK)) s_ok = 0;
    int Rv = 1;
    for (int i = 0; i < 8; ++i) {
      int r = load_i32_llc(&ctr[F_CREG + i * 16]);
      if (i == s_x) Rv = r;
    }
    s_R = Rv;
  }
  __syncthreads();
  const int xcd = s_x, rk = s_rk, R = s_R;
  if (!s_ok) return;

  unsigned short* repB = rep + (size_t)xcd * 4 * HP;
  const unsigned short* A0H = repB + (size_t)arow * 1024;
  const unsigned short* A0L = repB + HP + (size_t)arow * 1024;
  const unsigned short* A1H = repB + 2 * HP + (size_t)arow * 1024;
  const unsigned short* A1L = repB + 3 * HP + (size_t)arow * 1024;

  // distribution role (tid<512 only): plane pr, 16B chunk ch
  const int pr = (tid >> 7) & 3;
  const int ch = (tid & 127) * 8;
  const unsigned short* spBase =
      (pr == 0) ? hg0hi : (pr == 1) ? hg0lo : (pr == 2) ? hg1hi : hg1lo;
  unsigned short* dp = repB + pr * HP;

  const u32x4* wl0g = (const u32x4*)(Wlo0g + (size_t)bid * (KT0B * 64));
  const u32x4* wl1g = (const u32x4*)(Wlo1g + (size_t)bid * (KT1B * 64));
  const u32x4* wh1g = (const u32x4*)(Whi1g + (size_t)bid * (KT1B * 64));

  // slab source for chunk c, slab s
  auto slabSrc = [&](int c, int s) -> const u32x4* {
    if (c == 0) return (s < 16) ? wl0g + s * 64 : wl1g + (s - 16) * 64;
    if (c == 1) return (s < 12) ? wl0g + (16 + s) * 64 : wl1g + (s - 4) * 64;
    if (c == 2) return (s < 12) ? wl0g + (28 + s) * 64 : wl1g + (8 + s) * 64;
    if (c == 3) return (s < 16) ? wl1g + (32 + s) * 64 : wh1g + (36 + s) * 64; // s16..19 -> hi kt52..55
    return (s < 16) ? wl1g + (48 + s) * 64 : wh1g + (40 + s) * 64;            // s16..23 -> hi kt56..63
  };
  auto stageChunk = [&](int c, int buf) {
    const int n = kNSLAB[c];
    for (int s = w; s < n; s += 16)
      gll16((const void*)(slabSrc(c, s) + lane), (void*)&Wch[buf][s * 64]);
  };

  // prologue: stage C0 (buf0), C1 (buf1) of phase 0
  stageChunk(0, 0);
  stageChunk(1, 1);

  for (int p = 0; p < NPH; ++p) {
    const int nact0 = (p < 512) ? ncnt[p] : 0;
    const int nact1 = (p >= 1) ? ncnt[p - 1] : 0;
    const bool doL0 = isL0 && (p < 512) && (wl * 16 < nact0);
    const bool doL1 = !isL0 && (p >= 1) && (wl * 16 < nact1);

    f32x4 acc = (f32x4){0.f, 0.f, 0.f, 0.f};

    // ---- (A) dist (tid<512): issue LLC loads, wait, store into replica ----
    if (tid < 512) {
      const int ncopy = ncnt[p == 0 ? 0 : p - 1];
      const int par = (pr < 2) ? (p + 2) % 3 : (p + 1) % 3;
      const unsigned short* sp = spBase + (size_t)par * HP;
      uint4 dv0, dv1, dv2, dv3;
      const int dr0 = rk, dr1 = rk + R, dr2 = rk + 2 * R, dr3 = rk + 3 * R;
      if (dr0 < ncopy) dv0 = llc_load_issue((const unsigned*)(sp + dr0 * 1024 + ch));
      if (dr1 < ncopy) dv1 = llc_load_issue((const unsigned*)(sp + dr1 * 1024 + ch));
      if (dr2 < ncopy) dv2 = llc_load_issue((const unsigned*)(sp + dr2 * 1024 + ch));
      if (dr3 < ncopy) dv3 = llc_load_issue((const unsigned*)(sp + dr3 * 1024 + ch));
      vm_wait0();
      if (dr0 < ncopy) *(uint4*)(dp + dr0 * 1024 + ch) = dv0;
      if (dr1 < ncopy) *(uint4*)(dp + dr1 * 1024 + ch) = dv1;
      if (dr2 < ncopy) *(uint4*)(dp + dr2 * 1024 + ch) = dv2;
      if (dr3 < ncopy) *(uint4*)(dp + dr3 * 1024 + ch) = dv3;
      for (int r = rk + 4 * R; r < ncopy; r += R) {
        uint4 v = llc_load_issue((const unsigned*)(sp + r * 1024 + ch));
        vm_wait0();
        *(uint4*)(dp + r * 1024 + ch) = v;
      }
    }
    __syncthreads();                      // dist stores drained (vmcnt(0))

    // ---- (B) XCD barrier (LLC flags, stride-64 region) ----
    if (tid == 0) store_u32_llc((unsigned*)&ctr[F_XARR + xcd * 64 + rk], p + 1);
    if (tid < 64 && tid < R) {
      if (!spin_ge(&ctr[F_XARR + xcd * 64 + tid], p + 1)) s_ok = 0;
    }
    __syncthreads();
    if (!s_ok) break;
    inv_l1();                             // fresh L1 view of replica

    // ---- (C) 5-chunk GEMM, stage-1-ahead, layer-split waves ----
    // C0 (buf0): L0-waves X kt0-7 + D q0-7 ; L1-waves D q0-7
    {
      if (doL0) {
        const int tok = ib[(size_t)permA * 512 + p];
        const unsigned short* eh = embHi + tok * 256;
        const unsigned short* el = embLo + tok * 256;
#pragma unroll
        for (int kt = 0; kt < 8; ++kt) {
          const bf16x8 ah = asbf(*(const u32x4*)(eh + kt * 32 + slotE));
          const bf16x8 al = asbf(*(const u32x4*)(el + kt * 32 + slotE));
          MFMA3(acc, ah, al, asbf4(Wh0[kt * 64 + lane]), asbf(Wch[0][kt * 64 + lane]))
        }
#pragma unroll
        for (int q = 0; q < 8; ++q) {
          const bf16x8 ah = asbf(*(const u32x4*)(A0H + q * 32 + slotE));
          const bf16x8 al = asbf(*(const u32x4*)(A0L + q * 32 + slotE));
          MFMA3(acc, ah, al, asbf4(Wh0[(8 + q) * 64 + lane]),
                asbf(Wch[0][(8 + q) * 64 + lane]))
        }
      } else if (doL1) {
#pragma unroll
        for (int q = 0; q < 8; ++q) {
          const bf16x8 ah = asbf(*(const u32x4*)(A0H + q * 32 + slotE));
          const bf16x8 al = asbf(*(const u32x4*)(A0L + q * 32 + slotE));
          MFMA3(acc, ah, al, asbf4(Wh1[q * 64 + lane]),
                asbf(Wch[0][(16 + q) * 64 + lane]))
        }
      }
      __syncthreads();
    }
    // C1 (buf1): D q8..19 ; stage C2 -> buf0
    {
      stageChunk(2, 0);
      if (doL0) {
#pragma unroll
        for (int qq = 0; qq < 12; ++qq) {
          const int q = 8 + qq;
          const bf16x8 ah = asbf(*(const u32x4*)(A0H + q * 32 + slotE));
          const bf16x8 al = asbf(*(const u32x4*)(A0L + q * 32 + slotE));
          MFMA3(acc, ah, al, asbf4(Wh0[(8 + q) * 64 + lane]),
                asbf(Wch[1][qq * 64 + lane]))
        }
      } else if (doL1) {
#pragma unroll
        for (int qq = 0; qq < 12; ++qq) {
          const int q = 8 + qq;
          const bf16x8 ah = asbf(*(const u32x4*)(A0H + q * 32 + slotE));
          const bf16x8 al = asbf(*(const u32x4*)(A0L + q * 32 + slotE));
          MFMA3(acc, ah, al, asbf4(Wh1[q * 64 + lane]),
                asbf(Wch[1][(12 + qq) * 64 + lane]))
        }
      }
      __syncthreads();
    }
    // C2 (buf0): D q20..31 ; stage C3 -> buf1
    {
      stageChunk(3, 1);
      if (doL0) {
#pragma unroll
        for (int qq = 0; qq < 12; ++qq) {
          const int q = 20 + qq;
          const bf16x8 ah = asbf(*(const u32x4*)(A0H + q * 32 + slotE));
          const bf16x8 al = asbf(*(const u32x4*)(A0L + q * 32 + slotE));
          MFMA3(acc, ah, al, asbf4(Wh0[(8 + q) * 64 + lane]),
                asbf(Wch[0][qq * 64 + lane]))
        }
      } else if (doL1) {
#pragma unroll
        for (int qq = 0; qq < 12; ++qq) {
          const int q = 20 + qq;
          const bf16x8 ah = asbf(*(const u32x4*)(A0H + q * 32 + slotE));
          const bf16x8 al = asbf(*(const u32x4*)(A0L + q * 32 + slotE));
          MFMA3(acc, ah, al, asbf4(Wh1[q * 64 + lane]),
                asbf(Wch[0][(12 + qq) * 64 + lane]))
        }
      }
      __syncthreads();
    }
    // C3 (buf1): H1 q0..15 (L1 waves) ; stage C4 -> buf0
    {
      stageChunk(4, 0);
      if (doL1) {
#pragma unroll
        for (int q = 0; q < 16; ++q) {
          const bf16x8 ah = asbf(*(const u32x4*)(A1H + q * 32 + slotE));
          const bf16x8 al = asbf(*(const u32x4*)(A1L + q * 32 + slotE));
          MFMA3(acc, ah, al, asbf4(Wh1[(32 + q) * 64 + lane]),
                asbf(Wch[1][q * 64 + lane]))
        }
      }
      __syncthreads();
    }
    // C4 (buf0): H1 q16..31 (hi: kt48-51 LDS, kt52-55 from C3 buf1, kt56-63 own)
    {
      if (doL1) {
#pragma unroll
        for (int q = 16; q < 32; ++q) {
          const bf16x8 ah = asbf(*(const u32x4*)(A1H + q * 32 + slotE));
          const bf16x8 al = asbf(*(const u32x4*)(A1L + q * 32 + slotE));
          const bf16x8 bl = asbf(Wch[0][(q - 16) * 64 + lane]);
          bf16x8 bh;
          if (q < 20)      bh = asbf4(Wh1[(32 + q) * 64 + lane]);
          else if (q < 24) bh = asbf(Wch[1][(16 + q - 20) * 64 + lane]);
          else             bh = asbf(Wch[0][(16 + q - 24) * 64 + lane]);
          MFMA3(acc, ah, al, bh, bl)
        }
      }
      __syncthreads();
    }

    // ---- (D) stage next phase C0/C1 (constant data; lands during tail) ----
    if (p + 1 < NPH) {
      stageChunk(0, 0);
      stageChunk(1, 1);
    }

    // ---- (E) z exchange + parallel cells (halves) ----
    if (doL0) {
#pragma unroll
      for (int rr = 0; rr < 4; ++rr) zb[0][wl * 16 + lg4 + rr][lr] = acc[rr];
    }
    if (doL1) {
#pragma unroll
      for (int rr = 0; rr < 4; ++rr) zb[1][wl * 16 + lg4 + rr][lr] = acc[rr];
    }
    __syncthreads();

    if (isL0) {
      if (p < 512 && p < clen) {          // L0 cell, t = p
        const float zi = zb[0][srow][cu * 4 + 0] + bz[0];
        const float zj = zb[0][srow][cu * 4 + 1] + bz[1];
        const float zf = zb[0][srow][cu * 4 + 2] + bz[2];
        const float zo = zb[0][srow][cu * 4 + 3] + bz[3];
        const float nc = cr * sigm(zf + 1.0f) + sigm(zi) * tanh_f(zj);
        const float nh = tanh_f(nc) * sigm(zo);
        cr = nc;
        const unsigned short hh = f2bf(nh);
        const unsigned short hl = f2bf(nh - bf2f(hh));
        const size_t idx = (size_t)(p % 3) * HP + srow * 1024 + fpos;
        store_u16_llc(&hg0hi[idx], hh);
        store_u16_llc(&hg0lo[idx], hl);
      }
    } else {
      if (p >= 1 && (p - 1) < clen) {     // L1 cell, t = p-1
        const float zi = zb[1][srow][cu * 4 + 0] + bz[0];
        const float zj = zb[1][srow][cu * 4 + 1] + bz[1];
        const float zf = zb[1][srow][cu * 4 + 2] + bz[2];
        const float zo = zb[1][srow][cu * 4 + 3] + bz[3];
        const float nc = cr * sigm(zf + 1.0f) + sigm(zi) * tanh_f(zj);
        const float nh = tanh_f(nc) * sigm(zo);
        cr = nc;
        const unsigned short hh = f2bf(nh);
        const unsigned short hl = f2bf(nh - bf2f(hh));
        const size_t idx = (size_t)((p + 2) % 3) * HP + srow * 1024 + fpos;
        store_u16_llc(&hg1hi[idx], hh);
        store_u16_llc(&hg1lo[idx], hl);
        if (p - 1 == clen - 1) out[(size_t)cperm * 1024 + ug] = nh;
      }
    }

    // ---- (F) global barrier (LLC flags, r10-proven) ----
    vm_wait0();                           // h stores LLC-visible
    __syncthreads();
    if (tid == 0) store_u32_llc((unsigned*)&ctr[F_ARR + bid], p + 1);
    if (bid == 0) {
      if (tid < 256) {
        if (!spin_ge(&ctr[F_ARR + tid], p + 1)) s_ok = 0;
      }
      __syncthreads();
      if (tid == 0) store_u32_llc((unsigned*)&ctr[F_GO], p + 1);
    }
    if (tid == 0) {
      if (!spin_ge(&ctr[F_GO], p + 1)) s_ok = 0;
    }
    __syncthreads();
    if (!s_ok) break;
  }
}

// ======================= host launch =======================================

extern "C" void kernel_launch(void* const* d_in, const int* in_sizes, int n_in,
                              void* d_out, int out_size, void* d_ws, size_t ws_size,
                              hipStream_t stream) {
  const int*   ib   = (const int*)d_in[0];
  const int*   lens = (const int*)d_in[1];
  const float* emb  = (const float*)d_in[2];
  const float* W0   = (const float*)d_in[3];
  const float* b0   = (const float*)d_in[4];
  const float* W1   = (const float*)d_in[5];
  const float* b1   = (const float*)d_in[6];
  (void)in_sizes; (void)n_in; (void)out_size; (void)ws_size;

  char* ws = (char*)d_ws;
  size_t off = 0;
  auto alloc = [&](size_t bytes) { char* q = ws + off; off += (bytes + 255) & ~(size_t)255; return q; };

  int*            ctr   = (int*)alloc(8192);
  unsigned short* hg0hi = (unsigned short*)alloc((size_t)3 * HP * 2);
  unsigned short* hg0lo = (unsigned short*)alloc((size_t)3 * HP * 2);
  unsigned short* hg1hi = (unsigned short*)alloc((size_t)3 * HP * 2);
  unsigned short* hg1lo = (unsigned short*)alloc((size_t)3 * HP * 2);
  const size_t zero_bytes = off;          // ctr + h planes
  unsigned short* embHi = (unsigned short*)alloc(128 * 256 * 2);
  unsigned short* embLo = (unsigned short*)alloc(128 * 256 * 2);
  int*            perm  = (int*)alloc(4096);
  int*            lenS  = perm + 128;
  int*            ncnt  = perm + 256;
  unsigned short* rep   = (unsigned short*)alloc((size_t)8 * 4 * HP * 2);
  uint4*          Whi0  = (uint4*)alloc((size_t)NBLK * KT0B * 64 * 16);
  uint4*          Wlo0  = (uint4*)alloc((size_t)NBLK * KT0B * 64 * 16);
  uint4*          Whi1  = (uint4*)alloc((size_t)NBLK * KT1B * 64 * 16);
  uint4*          Wlo1  = (uint4*)alloc((size_t)NBLK * KT1B * 64 * 16);

  hipMemsetAsync(d_ws, 0, zero_bytes, stream);
  prep_sort<<<1, 512, 0, stream>>>(lens, perm, lenS, ncnt);
  prep_emb<<<128, 256, 0, stream>>>(emb, embHi, embLo);
  prep_wslab<<<(NBLK * KT0B * 64) / 256, 256, 0, stream>>>(W0, Whi0, Wlo0, KT0B);
  prep_wslab<<<(NBLK * KT1B * 64) / 256, 256, 0, stream>>>(W1, Whi1, Wlo1, KT1B);
  lstm_persist<<<NBLK, THREADS, 0, stream>>>(
      ib, b0, b1, Whi0, Wlo0, Whi1, Wlo1, embHi, embLo,
      perm, lenS, ncnt, hg0hi, hg0lo, hg1hi, hg1lo, rep, ctr, (float*)d_out);
}

// Round 12
// 16669.861 us; speedup vs baseline: 1.1064x; 1.1064x over previous
//
#include <hip/hip_runtime.h>

// ---------------------------------------------------------------------------
// 2-layer LSTM encoder, B=128 T=512 E=256 H=1024 (round 12).
// Persistent kernel: 256 blocks x 512 threads (8 waves, fused dual-layer).
// r12: SPLIT-PHASE dataflow sync (no monolithic global barrier):
//   synced half:  X-part -> wait h0arr(p-1) -> dist-h0 -> xbarA -> C0-C2
//                 -> L0 cell -> h0 stores -> set h0arr(p)
//   slack half:   wait h1arr(p-1) [1 phase of slack] -> dist-h1 -> xbarB
//                 -> C3-C4 -> L1 cell -> h1 stores -> set h1arr(p)
// The L1 tail overlaps other blocks' next-phase head; barriers are parallel
// 256-thread flag polls (1 LLC RT, no leader). Overwrite safety: dist-hX(p+1)
// waits hXarr >= p+1, set only after every consumer finished reading.
// Numerics: split-bf16 x3 MFMA (verified r1-r10). W-hi LDS-resident (W1
// kt56..63 streamed in C4); W-lo staged via async global_load_lds in 5 big
// double-buffered chunks, stage-1-ahead (r10-proven). LLC (sc0 sc1) flags.
// ---------------------------------------------------------------------------

namespace {
constexpr int NBLK = 256, THREADS = 512;
constexpr int KT0B = 40;           // L0 k-tiles of 32 (K=1280): 8 X + 32 D
constexpr int KT1B = 64;           // L1 k-tiles of 32 (K=2048): 32 D + 32 H1
constexpr int WH1KT = 56;          // W1-hi kt resident in LDS (56..63 streamed)
constexpr int NPH = 513;
constexpr int HP = 128 * 1024;     // u16 elems per h plane
constexpr int SPIN_CAP = 2000000;
// flag slots (u32 index into ctr[2048], zeroed per launch) — ALL LLC
constexpr int F_CREG  = 0;         // 8 x 16 (boot atomics)
constexpr int F_BOOT  = 128;
constexpr int F_H0ARR = 256;       // 256 slots: h0(p) ready per block
constexpr int F_H1ARR = 512;       // 256 slots: h1 ready per block
constexpr int F_XARRA = 768;       // 8 x 64: XCD barrier after dist-h0
constexpr int F_XARRB = 1280;      // 8 x 64: XCD barrier after dist-h1
constexpr int kNSLAB[5] = {24, 24, 24, 16, 24};
}

typedef __bf16 bf16x8 __attribute__((ext_vector_type(8)));
typedef float f32x4 __attribute__((ext_vector_type(4)));
typedef unsigned u32x4 __attribute__((ext_vector_type(4)));

__host__ __device__ __forceinline__ int fswz(int kk) {   // frag order within 32
  return ((kk & 15) >> 2) * 8 + (kk >> 4) * 4 + (kk & 3);
}

__device__ __forceinline__ unsigned short f2bf(float f) {
  unsigned u = __float_as_uint(f);
  u += 0x7fffu + ((u >> 16) & 1u);
  return (unsigned short)(u >> 16);
}
__device__ __forceinline__ float bf2f(unsigned short h) {
  return __uint_as_float(((unsigned)h) << 16);
}
__device__ __forceinline__ float sigm(float x) { return 1.0f / (1.0f + __expf(-x)); }
__device__ __forceinline__ float tanh_f(float x) {
  float e = __expf(-2.0f * fabsf(x));
  float r = (1.0f - e) / (1.0f + e);
  return x >= 0.0f ? r : -r;
}

// ---- LLC-coherent ops (bypass L1+L2) --------------------------------------
__device__ __forceinline__ int load_i32_llc(const int* p) {
  int v;
  asm volatile("global_load_dword %0, %1, off sc0 sc1\n\ts_waitcnt vmcnt(0)"
               : "=v"(v) : "v"(p) : "memory");
  return v;
}
__device__ __forceinline__ uint4 llc_load_issue(const unsigned* p) {
  uint4 v;
  asm volatile("global_load_dwordx4 %0, %1, off sc0 sc1" : "=v"(v) : "v"(p));
  return v;
}
__device__ __forceinline__ void vm_wait0() {
  asm volatile("s_waitcnt vmcnt(0)" ::: "memory");
  __builtin_amdgcn_sched_barrier(0);
}
__device__ __forceinline__ void store_u32_llc(unsigned* p, unsigned v) {
  asm volatile("global_store_dword %0, %1, off sc0 sc1" :: "v"(p), "v"(v) : "memory");
}
__device__ __forceinline__ void store_u16_llc(unsigned short* p, unsigned short v) {
  asm volatile("global_store_short %0, %1, off sc0 sc1" :: "v"(p), "v"(v) : "memory");
}
__device__ __forceinline__ void inv_l1() {
  asm volatile("buffer_inv" ::: "memory");
}
__device__ __forceinline__ int xcc_id() {
  int x;
  asm("s_getreg_b32 %0, hwreg(HW_REG_XCC_ID)" : "=s"(x));
  return x & 7;
}
__device__ __forceinline__ int spin_ge(int* p, int target) {
  for (int it = 0; it < SPIN_CAP; ++it) {
    if (load_i32_llc(p) >= target) return 1;
    __builtin_amdgcn_s_sleep(1);
  }
  return 0;
}
__device__ __forceinline__ bf16x8 asbf(u32x4 v) { return __builtin_bit_cast(bf16x8, v); }
__device__ __forceinline__ bf16x8 asbf4(uint4 v) { return __builtin_bit_cast(bf16x8, v); }

// async global -> LDS, 16B per lane (dest = wave-uniform base + lane*16)
typedef __attribute__((address_space(1))) void gas_void;
typedef __attribute__((address_space(3))) void las_void;
__device__ __forceinline__ void gll16(const void* g, void* l) {
  __builtin_amdgcn_global_load_lds((gas_void*)g, (las_void*)l, 16, 0, 0);
}

#define MFMA3(acc, ah, al, bh, bl)                                            \
  acc = __builtin_amdgcn_mfma_f32_16x16x32_bf16(ah, bh, acc, 0, 0, 0);        \
  acc = __builtin_amdgcn_mfma_f32_16x16x32_bf16(ah, bl, acc, 0, 0, 0);        \
  acc = __builtin_amdgcn_mfma_f32_16x16x32_bf16(al, bh, acc, 0, 0, 0);

// ======================= prep kernels =====================================

__global__ void prep_sort(const int* __restrict__ lens, int* __restrict__ perm,
                          int* __restrict__ lenS, int* __restrict__ ncnt) {
  __shared__ int k_[128], p_[128];
  const int tid = threadIdx.x;
  if (tid < 128) { k_[tid] = (lens[tid] << 8) | (127 - tid); p_[tid] = tid; }
  __syncthreads();
  for (int ph = 0; ph < 128; ++ph) {
    if (tid < 64) {
      int a = 2 * tid + (ph & 1), b = a + 1;
      if (b < 128 && k_[a] < k_[b]) {
        int tk = k_[a]; k_[a] = k_[b]; k_[b] = tk;
        int tp = p_[a]; p_[a] = p_[b]; p_[b] = tp;
      }
    }
    __syncthreads();
  }
  if (tid < 128) { perm[tid] = p_[tid]; lenS[tid] = k_[tid] >> 8; }
  if (tid < 512) {
    int c = 0;
    for (int i = 0; i < 128; ++i) c += ((k_[i] >> 8) > tid) ? 1 : 0;
    ncnt[tid] = c;
  }
}

__global__ void prep_emb(const float* __restrict__ emb,
                         unsigned short* __restrict__ ehi,
                         unsigned short* __restrict__ elo) {
  int i = blockIdx.x * 256 + threadIdx.x;   // 32768
  int row = i >> 8, e = i & 255;
  int pos = row * 256 + (e >> 5) * 32 + fswz(e & 31);
  float f = emb[i];
  unsigned short h = f2bf(f);
  ehi[pos] = h;
  elo[pos] = f2bf(f - bf2f(h));
}

// W[k][4096] -> per-block frag slabs: e = (blk*KT + kt)*64 + lane.
__global__ void prep_wslab(const float* __restrict__ W, uint4* __restrict__ Whi,
                           uint4* __restrict__ Wlo, int KT) {
  int e = blockIdx.x * 256 + threadIdx.x;
  int lane = e & 63;
  int kt = (e >> 6) % KT;
  int blk = e / (64 * KT);
  int cf = lane & 15;
  int g = cf & 3, ul = cf >> 2;
  int col = g * 1024 + blk * 4 + ul;
  int kbase = kt * 32 + ((lane >> 4) & 3) * 4;
  unsigned hi[8], lo[8];
#pragma unroll
  for (int j = 0; j < 8; ++j) {
    int k = kbase + (j & 3) + 16 * (j >> 2);
    float f = W[(size_t)k * 4096 + col];
    unsigned short h = f2bf(f);
    hi[j] = h;
    lo[j] = f2bf(f - bf2f(h));
  }
  uint4 vh, vl;
  vh.x = hi[0] | (hi[1] << 16); vh.y = hi[2] | (hi[3] << 16);
  vh.z = hi[4] | (hi[5] << 16); vh.w = hi[6] | (hi[7] << 16);
  vl.x = lo[0] | (lo[1] << 16); vl.y = lo[2] | (lo[3] << 16);
  vl.z = lo[4] | (lo[5] << 16); vl.w = lo[6] | (lo[7] << 16);
  Whi[e] = vh;
  Wlo[e] = vl;
}

// ======================= persistent kernel =================================

__global__ __launch_bounds__(THREADS, 1) void lstm_persist(
    const int* __restrict__ ib,
    const float* __restrict__ bias0, const float* __restrict__ bias1,
    const uint4* __restrict__ Whi0g, const uint4* __restrict__ Wlo0g,
    const uint4* __restrict__ Whi1g, const uint4* __restrict__ Wlo1g,
    const unsigned short* __restrict__ embHi, const unsigned short* __restrict__ embLo,
    const int* __restrict__ perm, const int* __restrict__ lenS,
    const int* __restrict__ ncnt,
    unsigned short* hg0hi, unsigned short* hg0lo,   // [3][128][1024] frag-order
    unsigned short* hg1hi, unsigned short* hg1lo,
    unsigned short* rep,                            // [8][4][128][1024]
    int* ctr, float* __restrict__ out) {
  const int bid = blockIdx.x;
  const int tid = threadIdx.x;
  const int w = tid >> 6;                 // wave 0..7 -> rows w*16..+15
  const int lane = tid & 63;
  const int lr = lane & 15;
  const int lg4 = ((lane >> 4) & 3) * 4;
  const int slotE = ((lane >> 4) & 3) * 8;  // frag u16 offset within 32-group
  const int arow = w * 16 + lr;           // GEMM A row for this lane
  const int srow = tid >> 2;              // cell row 0..127
  const int cu = tid & 3;                 // cell unit 0..3
  const int ug = bid * 4 + cu;            // global unit
  const int fpos = (ug >> 5) * 32 + fswz(ug & 31);
  const int permA = perm[arow];
  const int cperm = perm[srow];
  const int clen = lenS[srow];

  __shared__ uint4 Wh0[KT0B * 64];              // 40 KB
  __shared__ uint4 Wh1[WH1KT * 64];             // 56 KB
  __shared__ __align__(16) u32x4 Wch[2][24 * 64];  // 48 KB (2 x 24KB chunks)
  __shared__ float zb[128][17];                 // 8.5 KB (L0 then L1)
  __shared__ int s_x, s_rk, s_R, s_ok;

  // ---- one-time: W-hi slabs -> LDS ----
  {
    const uint4* s0 = Whi0g + (size_t)bid * (KT0B * 64);
    for (int i = tid; i < KT0B * 64; i += THREADS) Wh0[i] = s0[i];
    const uint4* s1 = Whi1g + (size_t)bid * (KT1B * 64);
    for (int i = tid; i < WH1KT * 64; i += THREADS) Wh1[i] = s1[i];
  }

  float bz0[4], bz1[4];
#pragma unroll
  for (int g = 0; g < 4; ++g) {
    bz0[g] = bias0[g * 1024 + ug];
    bz1[g] = bias1[g * 1024 + ug];
  }
  float c0r = 0.0f, c1r = 0.0f;

  // ---- bootstrap (LLC atomics, once) ----
  if (tid == 0) {
    s_ok = 1;
    int x = xcc_id();
    s_x = x;
    s_rk = atomicAdd(&ctr[F_CREG + x * 16], 1);
    vm_wait0();
    atomicAdd(&ctr[F_BOOT], 1);
    if (!spin_ge(&ctr[F_BOOT], NBLK)) s_ok = 0;
    int Rv = 1;
    for (int i = 0; i < 8; ++i) {
      int r = load_i32_llc(&ctr[F_CREG + i * 16]);
      if (i == s_x) Rv = r;
    }
    s_R = Rv;
  }
  __syncthreads();
  const int xcd = s_x, rk = s_rk, R = s_R;
  if (!s_ok) return;

  unsigned short* repB = rep + (size_t)xcd * 4 * HP;
  const unsigned short* A0H = repB + (size_t)arow * 1024;
  const unsigned short* A0L = repB + HP + (size_t)arow * 1024;
  const unsigned short* A1H = repB + 2 * HP + (size_t)arow * 1024;
  const unsigned short* A1L = repB + 3 * HP + (size_t)arow * 1024;

  // distribution roles (2 planes per dist; all 512 threads, 2 row-groups)
  const int dpl = tid >> 8;               // 0..1: hi/lo plane
  const int drh = (tid >> 7) & 1;         // row-group bit
  const int dch = (tid & 127) * 8;        // u16 chunk offset

  const u32x4* wl0g = (const u32x4*)(Wlo0g + (size_t)bid * (KT0B * 64));
  const u32x4* wl1g = (const u32x4*)(Wlo1g + (size_t)bid * (KT1B * 64));
  const u32x4* wh1g = (const u32x4*)(Whi1g + (size_t)bid * (KT1B * 64));

  auto slabSrc = [&](int c, int s) -> const u32x4* {
    if (c == 0) return (s < 16) ? wl0g + s * 64 : wl1g + (s - 16) * 64;
    if (c == 1) return (s < 12) ? wl0g + (16 + s) * 64 : wl1g + (s - 4) * 64;
    if (c == 2) return (s < 12) ? wl0g + (28 + s) * 64 : wl1g + (8 + s) * 64;
    if (c == 3) return wl1g + (32 + s) * 64;
    return (s < 16) ? wl1g + (48 + s) * 64 : wh1g + (40 + s) * 64;  // kt56..63
  };
  auto stageChunk = [&](int c, int buf) {
    const int n = kNSLAB[c];
    for (int s = w; s < n; s += 8)
      gll16((const void*)(slabSrc(c, s) + lane), (void*)&Wch[buf][s * 64]);
  };

  // prologue: stage C0 (buf0), C1 (buf1) of phase 0; drain before first use
  stageChunk(0, 0);
  stageChunk(1, 1);
  vm_wait0();
  __syncthreads();

  for (int p = 0; p < NPH; ++p) {
    const int nact0 = (p < 512) ? ncnt[p] : 0;
    const int nact1 = (p >= 1) ? ncnt[p - 1] : 0;
    const bool doL0 = (p < 512) && (w * 16 < nact0);
    const bool doL1 = (p >= 1) && (w * 16 < nact1);
    const int ncopy = ncnt[p == 0 ? 0 : p - 1];

    f32x4 acc0 = (f32x4){0.f, 0.f, 0.f, 0.f};
    f32x4 acc1 = (f32x4){0.f, 0.f, 0.f, 0.f};

    // ===== (A) X-part GEMM (no h dependency; Wch[0] slabs 0..7) =====
    if (doL0) {
      const int tok = ib[(size_t)permA * 512 + p];
      const unsigned short* eh = embHi + tok * 256;
      const unsigned short* el = embLo + tok * 256;
#pragma unroll
      for (int kt = 0; kt < 8; ++kt) {
        const bf16x8 ah = asbf(*(const u32x4*)(eh + kt * 32 + slotE));
        const bf16x8 al = asbf(*(const u32x4*)(el + kt * 32 + slotE));
        MFMA3(acc0, ah, al, asbf4(Wh0[kt * 64 + lane]), asbf(Wch[0][kt * 64 + lane]))
      }
    }

    // ===== (B) wait h0(p-1) ready (parallel 256-flag poll) =====
    if (tid < 256) {
      if (!spin_ge(&ctr[F_H0ARR + tid], p)) s_ok = 0;
    }
    __syncthreads();
    if (!s_ok) break;

    // ===== (C) dist-h0 -> replica planes 0,1 =====
    {
      const unsigned short* sp =
          (dpl ? hg0lo : hg0hi) + (size_t)((p + 2) % 3) * HP;
      unsigned short* dpp = repB + dpl * HP;
      for (int rb = rk + drh * R; rb < ncopy; rb += 4 * R) {
        const int r1 = rb + 2 * R;
        uint4 v0, v1;
        v0 = llc_load_issue((const unsigned*)(sp + rb * 1024 + dch));
        if (r1 < ncopy) v1 = llc_load_issue((const unsigned*)(sp + r1 * 1024 + dch));
        vm_wait0();
        *(uint4*)(dpp + rb * 1024 + dch) = v0;
        if (r1 < ncopy) *(uint4*)(dpp + r1 * 1024 + dch) = v1;
      }
    }
    __syncthreads();                      // dist stores drained

    // ===== (D) xbarA (XCD, LLC flags) + L1 inv =====
    if (tid == 0) store_u32_llc((unsigned*)&ctr[F_XARRA + xcd * 64 + rk], p + 1);
    if (tid < 64 && tid < R) {
      if (!spin_ge(&ctr[F_XARRA + xcd * 64 + tid], p + 1)) s_ok = 0;
    }
    __syncthreads();
    if (!s_ok) break;
    inv_l1();

    // ===== (E) C0-C2: D region (A0), both layers =====
    {   // C0 (buf0): D q0..7
      if (doL0 || doL1) {
#pragma unroll
        for (int q = 0; q < 8; ++q) {
          const bf16x8 ah = asbf(*(const u32x4*)(A0H + q * 32 + slotE));
          const bf16x8 al = asbf(*(const u32x4*)(A0L + q * 32 + slotE));
          if (doL0) {
            MFMA3(acc0, ah, al, asbf4(Wh0[(8 + q) * 64 + lane]),
                  asbf(Wch[0][(8 + q) * 64 + lane]))
          }
          if (doL1) {
            MFMA3(acc1, ah, al, asbf4(Wh1[q * 64 + lane]),
                  asbf(Wch[0][(16 + q) * 64 + lane]))
          }
        }
      }
      __syncthreads();
    }
    {   // C1 (buf1): D q8..19 ; stage C2 -> buf0
      stageChunk(2, 0);
      if (doL0 || doL1) {
#pragma unroll
        for (int qq = 0; qq < 12; ++qq) {
          const int q = 8 + qq;
          const bf16x8 ah = asbf(*(const u32x4*)(A0H + q * 32 + slotE));
          const bf16x8 al = asbf(*(const u32x4*)(A0L + q * 32 + slotE));
          if (doL0) {
            MFMA3(acc0, ah, al, asbf4(Wh0[(8 + q) * 64 + lane]),
                  asbf(Wch[1][qq * 64 + lane]))
          }
          if (doL1) {
            MFMA3(acc1, ah, al, asbf4(Wh1[q * 64 + lane]),
                  asbf(Wch[1][(12 + qq) * 64 + lane]))
          }
        }
      }
      __syncthreads();
    }
    {   // C2 (buf0): D q20..31 ; stage C3 -> buf1
      stageChunk(3, 1);
      if (doL0 || doL1) {
#pragma unroll
        for (int qq = 0; qq < 12; ++qq) {
          const int q = 20 + qq;
          const bf16x8 ah = asbf(*(const u32x4*)(A0H + q * 32 + slotE));
          const bf16x8 al = asbf(*(const u32x4*)(A0L + q * 32 + slotE));
          if (doL0) {
            MFMA3(acc0, ah, al, asbf4(Wh0[(8 + q) * 64 + lane]),
                  asbf(Wch[0][qq * 64 + lane]))
          }
          if (doL1) {
            MFMA3(acc1, ah, al, asbf4(Wh1[q * 64 + lane]),
                  asbf(Wch[0][(12 + qq) * 64 + lane]))
          }
        }
      }
      __syncthreads();
    }

    // ===== (F) L0 z-exchange + cell + h0 publish =====
    if (doL0) {
#pragma unroll
      for (int rr = 0; rr < 4; ++rr) zb[w * 16 + lg4 + rr][lr] = acc0[rr];
    }
    __syncthreads();
    if (p < 512 && p < clen) {
      const float zi = zb[srow][cu * 4 + 0] + bz0[0];
      const float zj = zb[srow][cu * 4 + 1] + bz0[1];
      const float zf = zb[srow][cu * 4 + 2] + bz0[2];
      const float zo = zb[srow][cu * 4 + 3] + bz0[3];
      const float nc = c0r * sigm(zf + 1.0f) + sigm(zi) * tanh_f(zj);
      const float nh = tanh_f(nc) * sigm(zo);
      c0r = nc;
      const unsigned short hh = f2bf(nh);
      const unsigned short hl = f2bf(nh - bf2f(hh));
      const size_t idx = (size_t)(p % 3) * HP + srow * 1024 + fpos;
      store_u16_llc(&hg0hi[idx], hh);
      store_u16_llc(&hg0lo[idx], hl);
    }
    vm_wait0();
    __syncthreads();                      // all h0 stores LLC-complete
    if (tid == 0) store_u32_llc((unsigned*)&ctr[F_H0ARR + bid], p + 1);

    // ===== (G) wait h1(p-2) ready (1 phase of slack; usually free) =====
    if (tid < 256) {
      if (!spin_ge(&ctr[F_H1ARR + tid], p)) s_ok = 0;
    }
    __syncthreads();
    if (!s_ok) break;

    // ===== (H) dist-h1 -> replica planes 2,3 =====
    {
      const unsigned short* sp =
          (dpl ? hg1lo : hg1hi) + (size_t)((p + 1) % 3) * HP;
      unsigned short* dpp = repB + (2 + dpl) * HP;
      for (int rb = rk + drh * R; rb < ncopy; rb += 4 * R) {
        const int r1 = rb + 2 * R;
        uint4 v0, v1;
        v0 = llc_load_issue((const unsigned*)(sp + rb * 1024 + dch));
        if (r1 < ncopy) v1 = llc_load_issue((const unsigned*)(sp + r1 * 1024 + dch));
        vm_wait0();
        *(uint4*)(dpp + rb * 1024 + dch) = v0;
        if (r1 < ncopy) *(uint4*)(dpp + r1 * 1024 + dch) = v1;
      }
    }
    __syncthreads();

    // ===== (I) xbarB (XCD) + L1 inv =====
    if (tid == 0) store_u32_llc((unsigned*)&ctr[F_XARRB + xcd * 64 + rk], p + 1);
    if (tid < 64 && tid < R) {
      if (!spin_ge(&ctr[F_XARRB + xcd * 64 + tid], p + 1)) s_ok = 0;
    }
    __syncthreads();
    if (!s_ok) break;
    inv_l1();

    // ===== (J) C3-C4: H1 region (A1), L1 only =====
    {   // C3 (buf1): H1 q0..15 ; stage C4 -> buf0
      stageChunk(4, 0);
      if (doL1) {
#pragma unroll
        for (int q = 0; q < 16; ++q) {
          const bf16x8 ah = asbf(*(const u32x4*)(A1H + q * 32 + slotE));
          const bf16x8 al = asbf(*(const u32x4*)(A1L + q * 32 + slotE));
          MFMA3(acc1, ah, al, asbf4(Wh1[(32 + q) * 64 + lane]),
                asbf(Wch[1][q * 64 + lane]))
        }
      }
      __syncthreads();
    }
    {   // C4 (buf0): H1 q16..31 (W1-hi kt56..63 streamed at slabs 16..23)
      if (doL1) {
#pragma unroll
        for (int q = 16; q < 32; ++q) {
          const bf16x8 ah = asbf(*(const u32x4*)(A1H + q * 32 + slotE));
          const bf16x8 al = asbf(*(const u32x4*)(A1L + q * 32 + slotE));
          const bf16x8 bl = asbf(Wch[0][(q - 16) * 64 + lane]);
          bf16x8 bh;
          if (q < 24) bh = asbf4(Wh1[(32 + q) * 64 + lane]);
          else        bh = asbf(Wch[0][(16 + q - 24) * 64 + lane]);
          MFMA3(acc1, ah, al, bh, bl)
        }
      }
      __syncthreads();
    }

    // ===== (K) stage next phase C0/C1 + L1 cell + h1 publish =====
    if (p + 1 < NPH) {
      stageChunk(0, 0);
      stageChunk(1, 1);
    }
    if (doL1) {
#pragma unroll
      for (int rr = 0; rr < 4; ++rr) zb[w * 16 + lg4 + rr][lr] = acc1[rr];
    }
    __syncthreads();
    if (p >= 1 && (p - 1) < clen) {
      const float zi = zb[srow][cu * 4 + 0] + bz1[0];
      const float zj = zb[srow][cu * 4 + 1] + bz1[1];
      const float zf = zb[srow][cu * 4 + 2] + bz1[2];
      const float zo = zb[srow][cu * 4 + 3] + bz1[3];
      const float nc = c1r * sigm(zf + 1.0f) + sigm(zi) * tanh_f(zj);
      const float nh = tanh_f(nc) * sigm(zo);
      c1r = nc;
      const unsigned short hh = f2bf(nh);
      const unsigned short hl = f2bf(nh - bf2f(hh));
      const size_t idx = (size_t)((p + 2) % 3) * HP + srow * 1024 + fpos;
      store_u16_llc(&hg1hi[idx], hh);
      store_u16_llc(&hg1lo[idx], hl);
      if (p - 1 == clen - 1) out[(size_t)cperm * 1024 + ug] = nh;
    }
    vm_wait0();                           // h1 stores + next-chunk glls done
    __syncthreads();
    if (tid == 0) store_u32_llc((unsigned*)&ctr[F_H1ARR + bid], p + 1);
  }
}

// ======================= host launch =======================================

extern "C" void kernel_launch(void* const* d_in, const int* in_sizes, int n_in,
                              void* d_out, int out_size, void* d_ws, size_t ws_size,
                              hipStream_t stream) {
  const int*   ib   = (const int*)d_in[0];
  const int*   lens = (const int*)d_in[1];
  const float* emb  = (const float*)d_in[2];
  const float* W0   = (const float*)d_in[3];
  const float* b0   = (const float*)d_in[4];
  const float* W1   = (const float*)d_in[5];
  const float* b1   = (const float*)d_in[6];
  (void)in_sizes; (void)n_in; (void)out_size; (void)ws_size;

  char* ws = (char*)d_ws;
  size_t off = 0;
  auto alloc = [&](size_t bytes) { char* q = ws + off; off += (bytes + 255) & ~(size_t)255; return q; };

  int*            ctr   = (int*)alloc(8192);
  unsigned short* hg0hi = (unsigned short*)alloc((size_t)3 * HP * 2);
  unsigned short* hg0lo = (unsigned short*)alloc((size_t)3 * HP * 2);
  unsigned short* hg1hi = (unsigned short*)alloc((size_t)3 * HP * 2);
  unsigned short* hg1lo = (unsigned short*)alloc((size_t)3 * HP * 2);
  const size_t zero_bytes = off;          // ctr + h planes
  unsigned short* embHi = (unsigned short*)alloc(128 * 256 * 2);
  unsigned short* embLo = (unsigned short*)alloc(128 * 256 * 2);
  int*            perm  = (int*)alloc(4096);
  int*            lenS  = perm + 128;
  int*            ncnt  = perm + 256;
  unsigned short* rep   = (unsigned short*)alloc((size_t)8 * 4 * HP * 2);
  uint4*          Whi0  = (uint4*)alloc((size_t)NBLK * KT0B * 64 * 16);
  uint4*          Wlo0  = (uint4*)alloc((size_t)NBLK * KT0B * 64 * 16);
  uint4*          Whi1  = (uint4*)alloc((size_t)NBLK * KT1B * 64 * 16);
  uint4*          Wlo1  = (uint4*)alloc((size_t)NBLK * KT1B * 64 * 16);

  hipMemsetAsync(d_ws, 0, zero_bytes, stream);
  prep_sort<<<1, 512, 0, stream>>>(lens, perm, lenS, ncnt);
  prep_emb<<<128, 256, 0, stream>>>(emb, embHi, embLo);
  prep_wslab<<<(NBLK * KT0B * 64) / 256, 256, 0, stream>>>(W0, Whi0, Wlo0, KT0B);
  prep_wslab<<<(NBLK * KT1B * 64) / 256, 256, 0, stream>>>(W1, Whi1, Wlo1, KT1B);
  lstm_persist<<<NBLK, THREADS, 0, stream>>>(
      ib, b0, b1, Whi0, Wlo0, Whi1, Wlo1, embHi, embLo,
      perm, lenS, ncnt, hg0hi, hg0lo, hg1hi, hg1lo, rep, ctr, (float*)d_out);
}

// Round 13
// 11560.719 us; speedup vs baseline: 1.5953x; 1.4419x over previous
//
#include <hip/hip_runtime.h>

// ---------------------------------------------------------------------------
// 2-layer LSTM encoder, B=128 T=512 E=256 H=1024 (round 13).
// Persistent kernel: 256 blocks x 512 threads (8 waves, fused dual-layer).
// Per phase p: L0 (t=p): z0=[x_p;h0(p-1)]@W0 -> h0(p)
//             L1 (t=p-1): z1=[h0(p-1);h1(p-2)]@W1 -> h1(p-1)
// r13 NUMERICS CHANGE: h = single fp16 plane (2^-11); W = fp16 hi + fp16 lo
// (2^-22). GEMM = 2 MFMA products (mfma_f32_16x16x32_f16) instead of 3.
// Halves A-replica bytes/loads, dist planes (4->2), h stores; MFMA -33%.
// Error model: ||W_row||~1.0, h_rms~0.4 -> absmax ~2-5e-4 < 9.77e-4 thr.
// Structure = r10-proven: W-hi LDS-resident (W1 kt56..63 streamed in C4),
// W-lo staged via async global_load_lds in 5 big dbuf chunks, LLC flags,
// monolithic global barrier, per-XCD replica dist, length-sorted gating.
// ---------------------------------------------------------------------------

namespace {
constexpr int NBLK = 256, THREADS = 512;
constexpr int KT0B = 40;           // L0 k-tiles of 32 (K=1280): 8 X + 32 D
constexpr int KT1B = 64;           // L1 k-tiles of 32 (K=2048): 32 D + 32 H1
constexpr int WH1KT = 56;          // W1-hi kt resident in LDS (56..63 streamed)
constexpr int NPH = 513;
constexpr int HPS = 128 * 1024;    // u16 elems per h plane (per layer)
constexpr int SPIN_CAP = 2000000;
// flag slots (u32 index into ctr, zeroed per launch) — ALL LLC (r10-proven)
constexpr int F_CREG = 0;          // 8 x 16 (boot atomics)
constexpr int F_BOOT = 128;
constexpr int F_ARR  = 256;        // 256 contiguous (global arrive)
constexpr int F_GO   = 520;
constexpr int F_XARR = 576;        // 8 x 64 (mid-phase XCD arrive)
constexpr int kNSLAB[5] = {24, 24, 24, 16, 24};
}

typedef _Float16 f16x8 __attribute__((ext_vector_type(8)));
typedef float f32x4 __attribute__((ext_vector_type(4)));
typedef unsigned u32x4 __attribute__((ext_vector_type(4)));

__host__ __device__ __forceinline__ int fswz(int kk) {   // frag order within 32
  return ((kk & 15) >> 2) * 8 + (kk >> 4) * 4 + (kk & 3);
}

__device__ __forceinline__ float sigm(float x) { return 1.0f / (1.0f + __expf(-x)); }
__device__ __forceinline__ float tanh_f(float x) {
  float e = __expf(-2.0f * fabsf(x));
  float r = (1.0f - e) / (1.0f + e);
  return x >= 0.0f ? r : -r;
}
__device__ __forceinline__ unsigned short f2h(float f) {  // RNE via v_cvt_f16_f32
  _Float16 h = (_Float16)f;
  return __builtin_bit_cast(unsigned short, h);
}

// ---- LLC-coherent ops (bypass L1+L2) --------------------------------------
__device__ __forceinline__ int load_i32_llc(const int* p) {
  int v;
  asm volatile("global_load_dword %0, %1, off sc0 sc1\n\ts_waitcnt vmcnt(0)"
               : "=v"(v) : "v"(p) : "memory");
  return v;
}
__device__ __forceinline__ uint4 llc_load_issue(const unsigned* p) {
  uint4 v;
  asm volatile("global_load_dwordx4 %0, %1, off sc0 sc1" : "=v"(v) : "v"(p));
  return v;
}
__device__ __forceinline__ void vm_wait0() {
  asm volatile("s_waitcnt vmcnt(0)" ::: "memory");
  __builtin_amdgcn_sched_barrier(0);
}
__device__ __forceinline__ void store_u32_llc(unsigned* p, unsigned v) {
  asm volatile("global_store_dword %0, %1, off sc0 sc1" :: "v"(p), "v"(v) : "memory");
}
__device__ __forceinline__ void store_u16_llc(unsigned short* p, unsigned short v) {
  asm volatile("global_store_short %0, %1, off sc0 sc1" :: "v"(p), "v"(v) : "memory");
}
__device__ __forceinline__ void inv_l1() {
  asm volatile("buffer_inv" ::: "memory");
}
__device__ __forceinline__ int xcc_id() {
  int x;
  asm("s_getreg_b32 %0, hwreg(HW_REG_XCC_ID)" : "=s"(x));
  return x & 7;
}
__device__ __forceinline__ int spin_ge(int* p, int target) {
  for (int it = 0; it < SPIN_CAP; ++it) {
    if (load_i32_llc(p) >= target) return 1;
    __builtin_amdgcn_s_sleep(1);
  }
  return 0;
}
__device__ __forceinline__ f16x8 ash(u32x4 v) { return __builtin_bit_cast(f16x8, v); }
__device__ __forceinline__ f16x8 ash4(uint4 v) { return __builtin_bit_cast(f16x8, v); }

// async global -> LDS, 16B per lane (dest = wave-uniform base + lane*16)
typedef __attribute__((address_space(1))) void gas_void;
typedef __attribute__((address_space(3))) void las_void;
__device__ __forceinline__ void gll16(const void* g, void* l) {
  __builtin_amdgcn_global_load_lds((gas_void*)g, (las_void*)l, 16, 0, 0);
}

#define MFMA2(acc, ah, bh, bl)                                                \
  acc = __builtin_amdgcn_mfma_f32_16x16x32_f16(ah, bh, acc, 0, 0, 0);         \
  acc = __builtin_amdgcn_mfma_f32_16x16x32_f16(ah, bl, acc, 0, 0, 0);

// ======================= prep kernels =====================================

__global__ void prep_sort(const int* __restrict__ lens, int* __restrict__ perm,
                          int* __restrict__ lenS, int* __restrict__ ncnt) {
  __shared__ int k_[128], p_[128];
  const int tid = threadIdx.x;
  if (tid < 128) { k_[tid] = (lens[tid] << 8) | (127 - tid); p_[tid] = tid; }
  __syncthreads();
  for (int ph = 0; ph < 128; ++ph) {
    if (tid < 64) {
      int a = 2 * tid + (ph & 1), b = a + 1;
      if (b < 128 && k_[a] < k_[b]) {
        int tk = k_[a]; k_[a] = k_[b]; k_[b] = tk;
        int tp = p_[a]; p_[a] = p_[b]; p_[b] = tp;
      }
    }
    __syncthreads();
  }
  if (tid < 128) { perm[tid] = p_[tid]; lenS[tid] = k_[tid] >> 8; }
  if (tid < 512) {
    int c = 0;
    for (int i = 0; i < 128; ++i) c += ((k_[i] >> 8) > tid) ? 1 : 0;
    ncnt[tid] = c;
  }
}

// emb -> single fp16 plane, fragment-interleaved order
__global__ void prep_emb(const float* __restrict__ emb,
                         unsigned short* __restrict__ ef) {
  int i = blockIdx.x * 256 + threadIdx.x;   // 32768
  int row = i >> 8, e = i & 255;
  int pos = row * 256 + (e >> 5) * 32 + fswz(e & 31);
  ef[pos] = f2h(emb[i]);
}

// W[k][4096] -> per-block frag slabs (fp16 hi/lo): e = (blk*KT + kt)*64 + lane.
__global__ void prep_wslab(const float* __restrict__ W, uint4* __restrict__ Whi,
                           uint4* __restrict__ Wlo, int KT) {
  int e = blockIdx.x * 256 + threadIdx.x;
  int lane = e & 63;
  int kt = (e >> 6) % KT;
  int blk = e / (64 * KT);
  int cf = lane & 15;
  int g = cf & 3, ul = cf >> 2;
  int col = g * 1024 + blk * 4 + ul;
  int kbase = kt * 32 + ((lane >> 4) & 3) * 4;
  unsigned hi[8], lo[8];
#pragma unroll
  for (int j = 0; j < 8; ++j) {
    int k = kbase + (j & 3) + 16 * (j >> 2);
    float f = W[(size_t)k * 4096 + col];
    _Float16 hf = (_Float16)f;
    float rem = f - (float)hf;
    hi[j] = __builtin_bit_cast(unsigned short, hf);
    lo[j] = __builtin_bit_cast(unsigned short, (_Float16)rem);
  }
  uint4 vh, vl;
  vh.x = hi[0] | (hi[1] << 16); vh.y = hi[2] | (hi[3] << 16);
  vh.z = hi[4] | (hi[5] << 16); vh.w = hi[6] | (hi[7] << 16);
  vl.x = lo[0] | (lo[1] << 16); vl.y = lo[2] | (lo[3] << 16);
  vl.z = lo[4] | (lo[5] << 16); vl.w = lo[6] | (lo[7] << 16);
  Whi[e] = vh;
  Wlo[e] = vl;
}

// ======================= persistent kernel =================================

__global__ __launch_bounds__(THREADS, 1) void lstm_persist(
    const int* __restrict__ ib,
    const float* __restrict__ bias0, const float* __restrict__ bias1,
    const uint4* __restrict__ Whi0g, const uint4* __restrict__ Wlo0g,
    const uint4* __restrict__ Whi1g, const uint4* __restrict__ Wlo1g,
    const unsigned short* __restrict__ embF,
    const int* __restrict__ perm, const int* __restrict__ lenS,
    const int* __restrict__ ncnt,
    unsigned short* hg0, unsigned short* hg1,   // [3][128][1024] f16 frag-order
    unsigned short* rep,                        // [8][2][128][1024] f16
    int* ctr, float* __restrict__ out) {
  const int bid = blockIdx.x;
  const int tid = threadIdx.x;
  const int w = tid >> 6;                 // wave 0..7 -> rows w*16..+15
  const int lane = tid & 63;
  const int lr = lane & 15;
  const int lg4 = ((lane >> 4) & 3) * 4;
  const int slotE = ((lane >> 4) & 3) * 8;  // frag u16 offset within 32-group
  const int arow = w * 16 + lr;           // GEMM A row for this lane
  const int srow = tid >> 2;              // cell row 0..127
  const int cu = tid & 3;                 // cell unit 0..3
  const int ug = bid * 4 + cu;            // global unit
  const int fpos = (ug >> 5) * 32 + fswz(ug & 31);
  const int permA = perm[arow];
  const int cperm = perm[srow];
  const int clen = lenS[srow];

  __shared__ uint4 Wh0[KT0B * 64];              // 40 KB
  __shared__ uint4 Wh1[WH1KT * 64];             // 56 KB
  __shared__ __align__(16) u32x4 Wch[2][24 * 64];  // 48 KB (2 x 24KB chunks)
  __shared__ float zb[128][17];                 // 8.5 KB (L0 then L1)
  __shared__ int s_x, s_rk, s_R, s_ok;

  // ---- one-time: W-hi slabs -> LDS ----
  {
    const uint4* s0 = Whi0g + (size_t)bid * (KT0B * 64);
    for (int i = tid; i < KT0B * 64; i += THREADS) Wh0[i] = s0[i];
    const uint4* s1 = Whi1g + (size_t)bid * (KT1B * 64);
    for (int i = tid; i < WH1KT * 64; i += THREADS) Wh1[i] = s1[i];
  }

  float bz0[4], bz1[4];
#pragma unroll
  for (int g = 0; g < 4; ++g) {
    bz0[g] = bias0[g * 1024 + ug];
    bz1[g] = bias1[g * 1024 + ug];
  }
  float c0r = 0.0f, c1r = 0.0f;

  // ---- bootstrap (LLC atomics, once) ----
  if (tid == 0) {
    s_ok = 1;
    int x = xcc_id();
    s_x = x;
    s_rk = atomicAdd(&ctr[F_CREG + x * 16], 1);
    vm_wait0();
    atomicAdd(&ctr[F_BOOT], 1);
    if (!spin_ge(&ctr[F_BOOT], NBLK)) s_ok = 0;
    int Rv = 1;
    for (int i = 0; i < 8; ++i) {
      int r = load_i32_llc(&ctr[F_CREG + i * 16]);
      if (i == s_x) Rv = r;
    }
    s_R = Rv;
  }
  __syncthreads();
  const int xcd = s_x, rk = s_rk, R = s_R;
  if (!s_ok) return;

  unsigned short* repB = rep + (size_t)xcd * 2 * HPS;
  const unsigned short* A0 = repB + (size_t)arow * 1024;          // h0 plane
  const unsigned short* A1 = repB + HPS + (size_t)arow * 1024;    // h1 plane

  // distribution role: plane pl (0=h0,1=h1), row-offset bit, 16B chunk
  const int pl = tid >> 8;                // 0..1
  const int rowoff = (tid >> 7) & 1;      // row pair bit
  const int ch = (tid & 127) * 8;         // u16 offset in row
  unsigned short* dp = repB + pl * HPS;

  const u32x4* wl0g = (const u32x4*)(Wlo0g + (size_t)bid * (KT0B * 64));
  const u32x4* wl1g = (const u32x4*)(Wlo1g + (size_t)bid * (KT1B * 64));
  const u32x4* wh1g = (const u32x4*)(Whi1g + (size_t)bid * (KT1B * 64));

  auto slabSrc = [&](int c, int s) -> const u32x4* {
    if (c == 0) return (s < 16) ? wl0g + s * 64 : wl1g + (s - 16) * 64;
    if (c == 1) return (s < 12) ? wl0g + (16 + s) * 64 : wl1g + (s - 4) * 64;
    if (c == 2) return (s < 12) ? wl0g + (28 + s) * 64 : wl1g + (8 + s) * 64;
    if (c == 3) return wl1g + (32 + s) * 64;
    return (s < 16) ? wl1g + (48 + s) * 64 : wh1g + (40 + s) * 64;  // kt56..63
  };
  auto stageChunk = [&](int c, int buf) {
    const int n = kNSLAB[c];
    for (int s = w; s < n; s += 8)
      gll16((const void*)(slabSrc(c, s) + lane), (void*)&Wch[buf][s * 64]);
  };

  // prologue: stage C0 (buf0), C1 (buf1) of phase 0
  stageChunk(0, 0);
  stageChunk(1, 1);

  for (int p = 0; p < NPH; ++p) {
    const int nact0 = (p < 512) ? ncnt[p] : 0;
    const int nact1 = (p >= 1) ? ncnt[p - 1] : 0;
    const bool doL0 = (p < 512) && (w * 16 < nact0);
    const bool doL1 = (p >= 1) && (w * 16 < nact1);

    f32x4 acc0 = (f32x4){0.f, 0.f, 0.f, 0.f};
    f32x4 acc1 = (f32x4){0.f, 0.f, 0.f, 0.f};

    // ---- (A) dist: h0(p-1) / h1(p-2) planes -> XCD replica ----
    {
      const int ncopy = ncnt[p == 0 ? 0 : p - 1];
      const unsigned short* sp =
          (pl == 0) ? (hg0 + (size_t)((p + 2) % 3) * HPS)
                    : (hg1 + (size_t)((p + 1) % 3) * HPS);
      const int step = 2 * R;
      const int dr0 = 2 * rk + rowoff;
      const int dr1 = dr0 + step, dr2 = dr0 + 2 * step, dr3 = dr0 + 3 * step;
      uint4 dv0, dv1, dv2, dv3;
      if (dr0 < ncopy) dv0 = llc_load_issue((const unsigned*)(sp + dr0 * 1024 + ch));
      if (dr1 < ncopy) dv1 = llc_load_issue((const unsigned*)(sp + dr1 * 1024 + ch));
      if (dr2 < ncopy) dv2 = llc_load_issue((const unsigned*)(sp + dr2 * 1024 + ch));
      if (dr3 < ncopy) dv3 = llc_load_issue((const unsigned*)(sp + dr3 * 1024 + ch));
      vm_wait0();
      if (dr0 < ncopy) *(uint4*)(dp + dr0 * 1024 + ch) = dv0;
      if (dr1 < ncopy) *(uint4*)(dp + dr1 * 1024 + ch) = dv1;
      if (dr2 < ncopy) *(uint4*)(dp + dr2 * 1024 + ch) = dv2;
      if (dr3 < ncopy) *(uint4*)(dp + dr3 * 1024 + ch) = dv3;
      for (int r = dr0 + 4 * step; r < ncopy; r += step) {
        uint4 v = llc_load_issue((const unsigned*)(sp + r * 1024 + ch));
        vm_wait0();
        *(uint4*)(dp + r * 1024 + ch) = v;
      }
    }
    __syncthreads();                      // dist stores drained (vmcnt(0))

    // ---- (B) XCD barrier (LLC flags, stride-64 region) ----
    if (tid == 0) store_u32_llc((unsigned*)&ctr[F_XARR + xcd * 64 + rk], p + 1);
    if (tid < 64 && tid < R) {
      if (!spin_ge(&ctr[F_XARR + xcd * 64 + tid], p + 1)) s_ok = 0;
    }
    __syncthreads();
    if (!s_ok) break;
    inv_l1();                             // fresh L1 view of replica

    // ---- (C) 5-chunk GEMM, stage-1-ahead ----
    // C0 (buf0): X kt0-7 + D q0..7 (L0) ; D q0..7 (L1)
    {
      if (doL0) {
        const int tok = ib[(size_t)permA * 512 + p];
        const unsigned short* ef = embF + tok * 256;
#pragma unroll
        for (int kt = 0; kt < 8; ++kt) {
          const f16x8 ah = ash(*(const u32x4*)(ef + kt * 32 + slotE));
          MFMA2(acc0, ah, ash4(Wh0[kt * 64 + lane]), ash(Wch[0][kt * 64 + lane]))
        }
      }
      if (doL0 || doL1) {
#pragma unroll
        for (int q = 0; q < 8; ++q) {
          const f16x8 ah = ash(*(const u32x4*)(A0 + q * 32 + slotE));
          if (doL0) {
            MFMA2(acc0, ah, ash4(Wh0[(8 + q) * 64 + lane]),
                  ash(Wch[0][(8 + q) * 64 + lane]))
          }
          if (doL1) {
            MFMA2(acc1, ah, ash4(Wh1[q * 64 + lane]),
                  ash(Wch[0][(16 + q) * 64 + lane]))
          }
        }
      }
      __syncthreads();
    }
    // C1 (buf1): D q8..19 ; stage C2 -> buf0
    {
      stageChunk(2, 0);
      if (doL0 || doL1) {
#pragma unroll
        for (int qq = 0; qq < 12; ++qq) {
          const int q = 8 + qq;
          const f16x8 ah = ash(*(const u32x4*)(A0 + q * 32 + slotE));
          if (doL0) {
            MFMA2(acc0, ah, ash4(Wh0[(8 + q) * 64 + lane]),
                  ash(Wch[1][qq * 64 + lane]))
          }
          if (doL1) {
            MFMA2(acc1, ah, ash4(Wh1[q * 64 + lane]),
                  ash(Wch[1][(12 + qq) * 64 + lane]))
          }
        }
      }
      __syncthreads();
    }
    // C2 (buf0): D q20..31 ; stage C3 -> buf1
    {
      stageChunk(3, 1);
      if (doL0 || doL1) {
#pragma unroll
        for (int qq = 0; qq < 12; ++qq) {
          const int q = 20 + qq;
          const f16x8 ah = ash(*(const u32x4*)(A0 + q * 32 + slotE));
          if (doL0) {
            MFMA2(acc0, ah, ash4(Wh0[(8 + q) * 64 + lane]),
                  ash(Wch[0][qq * 64 + lane]))
          }
          if (doL1) {
            MFMA2(acc1, ah, ash4(Wh1[q * 64 + lane]),
                  ash(Wch[0][(12 + qq) * 64 + lane]))
          }
        }
      }
      __syncthreads();
    }
    // C3 (buf1): H1 q0..15 ; stage C4 -> buf0
    {
      stageChunk(4, 0);
      if (doL1) {
#pragma unroll
        for (int q = 0; q < 16; ++q) {
          const f16x8 ah = ash(*(const u32x4*)(A1 + q * 32 + slotE));
          MFMA2(acc1, ah, ash4(Wh1[(32 + q) * 64 + lane]),
                ash(Wch[1][q * 64 + lane]))
        }
      }
      __syncthreads();
    }
    // C4 (buf0): H1 q16..31 (W1-hi kt56..63 streamed at slabs 16..23)
    {
      if (doL1) {
#pragma unroll
        for (int q = 16; q < 32; ++q) {
          const f16x8 ah = ash(*(const u32x4*)(A1 + q * 32 + slotE));
          const f16x8 bl = ash(Wch[0][(q - 16) * 64 + lane]);
          f16x8 bh;
          if (q < 24) bh = ash4(Wh1[(32 + q) * 64 + lane]);
          else        bh = ash(Wch[0][(16 + q - 24) * 64 + lane]);
          MFMA2(acc1, ah, bh, bl)
        }
      }
      __syncthreads();
    }

    // ---- (D) stage next phase C0/C1 (constant data; lands during tail) ----
    if (p + 1 < NPH) {
      stageChunk(0, 0);
      stageChunk(1, 1);
    }

    // ---- (E) z exchange (zb reused) + cells ----
    if (doL0) {
#pragma unroll
      for (int rr = 0; rr < 4; ++rr) zb[w * 16 + lg4 + rr][lr] = acc0[rr];
    }
    __syncthreads();
    const bool act0 = (p < 512) && (p < clen);
    float z0i = 0, z0j = 0, z0f = 0, z0o = 0;
    if (act0) {
      z0i = zb[srow][cu * 4 + 0] + bz0[0];
      z0j = zb[srow][cu * 4 + 1] + bz0[1];
      z0f = zb[srow][cu * 4 + 2] + bz0[2];
      z0o = zb[srow][cu * 4 + 3] + bz0[3];
    }
    __syncthreads();
    if (doL1) {
#pragma unroll
      for (int rr = 0; rr < 4; ++rr) zb[w * 16 + lg4 + rr][lr] = acc1[rr];
    }
    if (act0) {                           // L0 cell overlaps L1 z-exchange
      const float nc = c0r * sigm(z0f + 1.0f) + sigm(z0i) * tanh_f(z0j);
      const float nh = tanh_f(nc) * sigm(z0o);
      c0r = nc;
      store_u16_llc(&hg0[(size_t)(p % 3) * HPS + srow * 1024 + fpos], f2h(nh));
    }
    __syncthreads();
    if (p >= 1 && (p - 1) < clen) {       // L1 cell, t = p-1
      const float z1i = zb[srow][cu * 4 + 0] + bz1[0];
      const float z1j = zb[srow][cu * 4 + 1] + bz1[1];
      const float z1f = zb[srow][cu * 4 + 2] + bz1[2];
      const float z1o = zb[srow][cu * 4 + 3] + bz1[3];
      const float nc = c1r * sigm(z1f + 1.0f) + sigm(z1i) * tanh_f(z1j);
      const float nh = tanh_f(nc) * sigm(z1o);
      c1r = nc;
      store_u16_llc(&hg1[(size_t)((p + 2) % 3) * HPS + srow * 1024 + fpos], f2h(nh));
      if (p - 1 == clen - 1) out[(size_t)cperm * 1024 + ug] = nh;
    }

    // ---- (F) global barrier (LLC flags, r10-proven) ----
    vm_wait0();                           // h stores LLC-visible
    __syncthreads();
    if (tid == 0) store_u32_llc((unsigned*)&ctr[F_ARR + bid], p + 1);
    if (bid == 0) {
      if (tid < 256) {
        if (!spin_ge(&ctr[F_ARR + tid], p + 1)) s_ok = 0;
      }
      __syncthreads();
      if (tid == 0) store_u32_llc((unsigned*)&ctr[F_GO], p + 1);
    }
    if (tid == 0) {
      if (!spin_ge(&ctr[F_GO], p + 1)) s_ok = 0;
    }
    __syncthreads();
    if (!s_ok) break;
  }
}

// ======================= host launch =======================================

extern "C" void kernel_launch(void* const* d_in, const int* in_sizes, int n_in,
                              void* d_out, int out_size, void* d_ws, size_t ws_size,
                              hipStream_t stream) {
  const int*   ib   = (const int*)d_in[0];
  const int*   lens = (const int*)d_in[1];
  const float* emb  = (const float*)d_in[2];
  const float* W0   = (const float*)d_in[3];
  const float* b0   = (const float*)d_in[4];
  const float* W1   = (const float*)d_in[5];
  const float* b1   = (const float*)d_in[6];
  (void)in_sizes; (void)n_in; (void)out_size; (void)ws_size;

  char* ws = (char*)d_ws;
  size_t off = 0;
  auto alloc = [&](size_t bytes) { char* q = ws + off; off += (bytes + 255) & ~(size_t)255; return q; };

  int*            ctr  = (int*)alloc(8192);
  unsigned short* hg0  = (unsigned short*)alloc((size_t)3 * HPS * 2);
  unsigned short* hg1  = (unsigned short*)alloc((size_t)3 * HPS * 2);
  const size_t zero_bytes = off;          // ctr + h planes
  unsigned short* embF = (unsigned short*)alloc(128 * 256 * 2);
  int*            perm = (int*)alloc(4096);
  int*            lenS = perm + 128;
  int*            ncnt = perm + 256;
  unsigned short* rep  = (unsigned short*)alloc((size_t)8 * 2 * HPS * 2);
  uint4*          Whi0 = (uint4*)alloc((size_t)NBLK * KT0B * 64 * 16);
  uint4*          Wlo0 = (uint4*)alloc((size_t)NBLK * KT0B * 64 * 16);
  uint4*          Whi1 = (uint4*)alloc((size_t)NBLK * KT1B * 64 * 16);
  uint4*          Wlo1 = (uint4*)alloc((size_t)NBLK * KT1B * 64 * 16);

  hipMemsetAsync(d_ws, 0, zero_bytes, stream);
  prep_sort<<<1, 512, 0, stream>>>(lens, perm, lenS, ncnt);
  prep_emb<<<128, 256, 0, stream>>>(emb, embF);
  prep_wslab<<<(NBLK * KT0B * 64) / 256, 256, 0, stream>>>(W0, Whi0, Wlo0, KT0B);
  prep_wslab<<<(NBLK * KT1B * 64) / 256, 256, 0, stream>>>(W1, Whi1, Wlo1, KT1B);
  lstm_persist<<<NBLK, THREADS, 0, stream>>>(
      ib, b0, b1, Whi0, Wlo0, Whi1, Wlo1, embF,
      perm, lenS, ncnt, hg0, hg1, rep, ctr, (float*)d_out);
}

// Round 14
// 9093.959 us; speedup vs baseline: 2.0280x; 1.2713x over previous
//
#include <hip/hip_runtime.h>

// ---------------------------------------------------------------------------
// 2-layer LSTM encoder, B=128 T=512 E=256 H=1024 (round 14).
// Persistent kernel: 256 blocks x 512 threads (8 waves, fused dual-layer).
// Per phase p: L0 (t=p): z0=[x_p;h0(p-1)]@W0 -> h0(p)
//             L1 (t=p-1): z1=[h0(p-1);h1(p-2)]@W1 -> h1(p-1)
// r14 NUMERICS: W = fp16 single-plane (RNE), FULLY LDS-RESIDENT (104 KB);
// h = fp16 plane (r13-verified). 1 MFMA/kt (was 2). NO W streaming, NO
// chunk machinery, NO internal GEMM barriers. Error model: W-sys 5e-4 +
// r13's 2.44e-4 -> ~5-7e-4 < 9.77e-4 threshold (revert to r13 if exceeded).
// Structure: per-XCD replica dist (overlapped with X-part GEMM), XCD barrier
// + inv_l1, single long GEMM body, fused cells, leaderless 256-flag global
// barrier (all LLC sc0 sc1 flags — r10/r12-proven). Length-sorted gating.
// ---------------------------------------------------------------------------

namespace {
constexpr int NBLK = 256, THREADS = 512;
constexpr int KT0B = 40;           // L0 k-tiles of 32 (K=1280): 8 X + 32 D
constexpr int KT1B = 64;           // L1 k-tiles of 32 (K=2048): 32 D + 32 H1
constexpr int NPH = 513;
constexpr int HPS = 128 * 1024;    // u16 elems per h plane (per layer)
constexpr int SPIN_CAP = 2000000;
// flag slots (u32 index into ctr, zeroed per launch) — ALL LLC
constexpr int F_CREG = 0;          // 8 x 16 (boot atomics)
constexpr int F_BOOT = 128;
constexpr int F_ARR  = 256;        // 256 contiguous (global arrive)
constexpr int F_XARR = 576;        // 8 x 64 (mid-phase XCD arrive)
}

typedef _Float16 f16x8 __attribute__((ext_vector_type(8)));
typedef float f32x4 __attribute__((ext_vector_type(4)));
typedef unsigned u32x4 __attribute__((ext_vector_type(4)));

__host__ __device__ __forceinline__ int fswz(int kk) {   // frag order within 32
  return ((kk & 15) >> 2) * 8 + (kk >> 4) * 4 + (kk & 3);
}

__device__ __forceinline__ float sigm(float x) { return 1.0f / (1.0f + __expf(-x)); }
__device__ __forceinline__ float tanh_f(float x) {
  float e = __expf(-2.0f * fabsf(x));
  float r = (1.0f - e) / (1.0f + e);
  return x >= 0.0f ? r : -r;
}
__device__ __forceinline__ unsigned short f2h(float f) {
  _Float16 h = (_Float16)f;
  return __builtin_bit_cast(unsigned short, h);
}

// ---- LLC-coherent ops (bypass L1+L2) --------------------------------------
__device__ __forceinline__ int load_i32_llc(const int* p) {
  int v;
  asm volatile("global_load_dword %0, %1, off sc0 sc1\n\ts_waitcnt vmcnt(0)"
               : "=v"(v) : "v"(p) : "memory");
  return v;
}
__device__ __forceinline__ uint4 llc_load_issue(const unsigned* p) {
  uint4 v;
  asm volatile("global_load_dwordx4 %0, %1, off sc0 sc1" : "=v"(v) : "v"(p));
  return v;
}
__device__ __forceinline__ void vm_wait0() {
  asm volatile("s_waitcnt vmcnt(0)" ::: "memory");
  __builtin_amdgcn_sched_barrier(0);
}
__device__ __forceinline__ void store_u32_llc(unsigned* p, unsigned v) {
  asm volatile("global_store_dword %0, %1, off sc0 sc1" :: "v"(p), "v"(v) : "memory");
}
__device__ __forceinline__ void store_u16_llc(unsigned short* p, unsigned short v) {
  asm volatile("global_store_short %0, %1, off sc0 sc1" :: "v"(p), "v"(v) : "memory");
}
__device__ __forceinline__ void inv_l1() {
  asm volatile("buffer_inv" ::: "memory");
}
__device__ __forceinline__ int xcc_id() {
  int x;
  asm("s_getreg_b32 %0, hwreg(HW_REG_XCC_ID)" : "=s"(x));
  return x & 7;
}
__device__ __forceinline__ int spin_ge(int* p, int target) {
  for (int it = 0; it < SPIN_CAP; ++it) {
    if (load_i32_llc(p) >= target) return 1;
    __builtin_amdgcn_s_sleep(1);
  }
  return 0;
}
__device__ __forceinline__ f16x8 ash(u32x4 v) { return __builtin_bit_cast(f16x8, v); }
__device__ __forceinline__ f16x8 ash4(uint4 v) { return __builtin_bit_cast(f16x8, v); }

#define MFMA1(acc, ah, bh)                                                    \
  acc = __builtin_amdgcn_mfma_f32_16x16x32_f16(ah, bh, acc, 0, 0, 0);

// ======================= prep kernels =====================================

__global__ void prep_sort(const int* __restrict__ lens, int* __restrict__ perm,
                          int* __restrict__ lenS, int* __restrict__ ncnt) {
  __shared__ int k_[128], p_[128];
  const int tid = threadIdx.x;
  if (tid < 128) { k_[tid] = (lens[tid] << 8) | (127 - tid); p_[tid] = tid; }
  __syncthreads();
  for (int ph = 0; ph < 128; ++ph) {
    if (tid < 64) {
      int a = 2 * tid + (ph & 1), b = a + 1;
      if (b < 128 && k_[a] < k_[b]) {
        int tk = k_[a]; k_[a] = k_[b]; k_[b] = tk;
        int tp = p_[a]; p_[a] = p_[b]; p_[b] = tp;
      }
    }
    __syncthreads();
  }
  if (tid < 128) { perm[tid] = p_[tid]; lenS[tid] = k_[tid] >> 8; }
  if (tid < 512) {
    int c = 0;
    for (int i = 0; i < 128; ++i) c += ((k_[i] >> 8) > tid) ? 1 : 0;
    ncnt[tid] = c;
  }
}

// emb -> single fp16 plane, fragment-interleaved order
__global__ void prep_emb(const float* __restrict__ emb,
                         unsigned short* __restrict__ ef) {
  int i = blockIdx.x * 256 + threadIdx.x;   // 32768
  int row = i >> 8, e = i & 255;
  int pos = row * 256 + (e >> 5) * 32 + fswz(e & 31);
  ef[pos] = f2h(emb[i]);
}

// W[k][4096] -> per-block fp16 frag slabs: e = (blk*KT + kt)*64 + lane.
__global__ void prep_wslab(const float* __restrict__ W, uint4* __restrict__ Whi,
                           int KT) {
  int e = blockIdx.x * 256 + threadIdx.x;
  int lane = e & 63;
  int kt = (e >> 6) % KT;
  int blk = e / (64 * KT);
  int cf = lane & 15;
  int g = cf & 3, ul = cf >> 2;
  int col = g * 1024 + blk * 4 + ul;
  int kbase = kt * 32 + ((lane >> 4) & 3) * 4;
  unsigned hi[8];
#pragma unroll
  for (int j = 0; j < 8; ++j) {
    int k = kbase + (j & 3) + 16 * (j >> 2);
    float f = W[(size_t)k * 4096 + col];
    hi[j] = __builtin_bit_cast(unsigned short, (_Float16)f);
  }
  uint4 vh;
  vh.x = hi[0] | (hi[1] << 16); vh.y = hi[2] | (hi[3] << 16);
  vh.z = hi[4] | (hi[5] << 16); vh.w = hi[6] | (hi[7] << 16);
  Whi[e] = vh;
}

// ======================= persistent kernel =================================

__global__ __launch_bounds__(THREADS, 1) void lstm_persist(
    const int* __restrict__ ib,
    const float* __restrict__ bias0, const float* __restrict__ bias1,
    const uint4* __restrict__ Whi0g, const uint4* __restrict__ Whi1g,
    const unsigned short* __restrict__ embF,
    const int* __restrict__ perm, const int* __restrict__ lenS,
    const int* __restrict__ ncnt,
    unsigned short* hg0, unsigned short* hg1,   // [3][128][1024] f16 frag-order
    unsigned short* rep,                        // [8][2][128][1024] f16
    int* ctr, float* __restrict__ out) {
  const int bid = blockIdx.x;
  const int tid = threadIdx.x;
  const int w = tid >> 6;                 // wave 0..7 -> rows w*16..+15
  const int lane = tid & 63;
  const int lr = lane & 15;
  const int lg4 = ((lane >> 4) & 3) * 4;
  const int slotE = ((lane >> 4) & 3) * 8;  // frag u16 offset within 32-group
  const int arow = w * 16 + lr;           // GEMM A row for this lane
  const int srow = tid >> 2;              // cell row 0..127
  const int cu = tid & 3;                 // cell unit 0..3
  const int ug = bid * 4 + cu;            // global unit
  const int fpos = (ug >> 5) * 32 + fswz(ug & 31);
  const int permA = perm[arow];
  const int cperm = perm[srow];
  const int clen = lenS[srow];

  __shared__ uint4 Wh0[KT0B * 64];              // 40 KB
  __shared__ uint4 Wh1[KT1B * 64];              // 64 KB
  __shared__ float zb[128][17];                 // 8.5 KB (L0 then L1)
  __shared__ int s_x, s_rk, s_R, s_ok;

  // ---- one-time: W fp16 slabs -> LDS (fully resident) ----
  {
    const uint4* s0 = Whi0g + (size_t)bid * (KT0B * 64);
    for (int i = tid; i < KT0B * 64; i += THREADS) Wh0[i] = s0[i];
    const uint4* s1 = Whi1g + (size_t)bid * (KT1B * 64);
    for (int i = tid; i < KT1B * 64; i += THREADS) Wh1[i] = s1[i];
  }

  float bz0[4], bz1[4];
#pragma unroll
  for (int g = 0; g < 4; ++g) {
    bz0[g] = bias0[g * 1024 + ug];
    bz1[g] = bias1[g * 1024 + ug];
  }
  float c0r = 0.0f, c1r = 0.0f;

  // ---- bootstrap (LLC atomics, once) ----
  if (tid == 0) {
    s_ok = 1;
    int x = xcc_id();
    s_x = x;
    s_rk = atomicAdd(&ctr[F_CREG + x * 16], 1);
    vm_wait0();
    atomicAdd(&ctr[F_BOOT], 1);
    if (!spin_ge(&ctr[F_BOOT], NBLK)) s_ok = 0;
    int Rv = 1;
    for (int i = 0; i < 8; ++i) {
      int r = load_i32_llc(&ctr[F_CREG + i * 16]);
      if (i == s_x) Rv = r;
    }
    s_R = Rv;
  }
  __syncthreads();
  const int xcd = s_x, rk = s_rk, R = s_R;
  if (!s_ok) return;

  unsigned short* repB = rep + (size_t)xcd * 2 * HPS;
  const unsigned short* A0 = repB + (size_t)arow * 1024;          // h0 plane
  const unsigned short* A1 = repB + HPS + (size_t)arow * 1024;    // h1 plane

  // distribution role: plane pl (0=h0,1=h1), row-offset bit, 16B chunk
  const int pl = tid >> 8;                // 0..1
  const int rowoff = (tid >> 7) & 1;      // row pair bit
  const int ch = (tid & 127) * 8;         // u16 offset in row
  unsigned short* dp = repB + pl * HPS;

  for (int p = 0; p < NPH; ++p) {
    const int nact0 = (p < 512) ? ncnt[p] : 0;
    const int nact1 = (p >= 1) ? ncnt[p - 1] : 0;
    const bool doL0 = (p < 512) && (w * 16 < nact0);
    const bool doL1 = (p >= 1) && (w * 16 < nact1);
    const int ncopy = ncnt[p == 0 ? 0 : p - 1];

    f32x4 acc0 = (f32x4){0.f, 0.f, 0.f, 0.f};
    f32x4 acc1 = (f32x4){0.f, 0.f, 0.f, 0.f};

    // ---- (A) dist: ISSUE LLC loads (h0(p-1) / h1(p-2) planes) ----
    const unsigned short* sp =
        (pl == 0) ? (hg0 + (size_t)((p + 2) % 3) * HPS)
                  : (hg1 + (size_t)((p + 1) % 3) * HPS);
    const int step = 2 * R;
    const int dr0 = 2 * rk + rowoff;
    const int dr1 = dr0 + step, dr2 = dr0 + 2 * step, dr3 = dr0 + 3 * step;
    uint4 dv0, dv1, dv2, dv3;
    if (dr0 < ncopy) dv0 = llc_load_issue((const unsigned*)(sp + dr0 * 1024 + ch));
    if (dr1 < ncopy) dv1 = llc_load_issue((const unsigned*)(sp + dr1 * 1024 + ch));
    if (dr2 < ncopy) dv2 = llc_load_issue((const unsigned*)(sp + dr2 * 1024 + ch));
    if (dr3 < ncopy) dv3 = llc_load_issue((const unsigned*)(sp + dr3 * 1024 + ch));

    // ---- (B) X-part GEMM (emb + LDS W0; overlaps dist latency) ----
    if (doL0) {
      const int tok = ib[(size_t)permA * 512 + p];
      const unsigned short* ef = embF + tok * 256;
#pragma unroll
      for (int kt = 0; kt < 8; ++kt) {
        const f16x8 ah = ash(*(const u32x4*)(ef + kt * 32 + slotE));
        MFMA1(acc0, ah, ash4(Wh0[kt * 64 + lane]))
      }
    }

    // ---- (C) finish dist: wait + store into replica (plain L2 stores) ----
    vm_wait0();
    if (dr0 < ncopy) *(uint4*)(dp + dr0 * 1024 + ch) = dv0;
    if (dr1 < ncopy) *(uint4*)(dp + dr1 * 1024 + ch) = dv1;
    if (dr2 < ncopy) *(uint4*)(dp + dr2 * 1024 + ch) = dv2;
    if (dr3 < ncopy) *(uint4*)(dp + dr3 * 1024 + ch) = dv3;
    for (int r = dr0 + 4 * step; r < ncopy; r += step) {
      uint4 v = llc_load_issue((const unsigned*)(sp + r * 1024 + ch));
      vm_wait0();
      *(uint4*)(dp + r * 1024 + ch) = v;
    }
    __syncthreads();                      // dist stores drained (vmcnt(0))

    // ---- (D) XCD barrier (LLC flags) + L1 inv ----
    if (tid == 0) store_u32_llc((unsigned*)&ctr[F_XARR + xcd * 64 + rk], p + 1);
    if (tid < 64 && tid < R) {
      if (!spin_ge(&ctr[F_XARR + xcd * 64 + tid], p + 1)) s_ok = 0;
    }
    __syncthreads();
    if (!s_ok) break;
    inv_l1();                             // fresh L1 view of replica

    // ---- (E) main GEMM body: D-part + H1-part, no internal barriers ----
    if (doL0 || doL1) {
#pragma unroll 8
      for (int q = 0; q < 32; ++q) {
        const f16x8 ah = ash(*(const u32x4*)(A0 + q * 32 + slotE));
        if (doL0) { MFMA1(acc0, ah, ash4(Wh0[(8 + q) * 64 + lane])) }
        if (doL1) { MFMA1(acc1, ah, ash4(Wh1[q * 64 + lane])) }
      }
    }
    if (doL1) {
#pragma unroll 8
      for (int q = 0; q < 32; ++q) {
        const f16x8 ah = ash(*(const u32x4*)(A1 + q * 32 + slotE));
        MFMA1(acc1, ah, ash4(Wh1[(32 + q) * 64 + lane]))
      }
    }

    // ---- (F) z exchange (zb reused) + cells ----
    __syncthreads();                      // zb free (prev phase done)
    if (doL0) {
#pragma unroll
      for (int rr = 0; rr < 4; ++rr) zb[w * 16 + lg4 + rr][lr] = acc0[rr];
    }
    __syncthreads();
    const bool act0 = (p < 512) && (p < clen);
    float z0i = 0, z0j = 0, z0f = 0, z0o = 0;
    if (act0) {
      z0i = zb[srow][cu * 4 + 0] + bz0[0];
      z0j = zb[srow][cu * 4 + 1] + bz0[1];
      z0f = zb[srow][cu * 4 + 2] + bz0[2];
      z0o = zb[srow][cu * 4 + 3] + bz0[3];
    }
    __syncthreads();
    if (doL1) {
#pragma unroll
      for (int rr = 0; rr < 4; ++rr) zb[w * 16 + lg4 + rr][lr] = acc1[rr];
    }
    if (act0) {                           // L0 cell overlaps L1 z-exchange
      const float nc = c0r * sigm(z0f + 1.0f) + sigm(z0i) * tanh_f(z0j);
      const float nh = tanh_f(nc) * sigm(z0o);
      c0r = nc;
      store_u16_llc(&hg0[(size_t)(p % 3) * HPS + srow * 1024 + fpos], f2h(nh));
    }
    __syncthreads();
    if (p >= 1 && (p - 1) < clen) {       // L1 cell, t = p-1
      const float z1i = zb[srow][cu * 4 + 0] + bz1[0];
      const float z1j = zb[srow][cu * 4 + 1] + bz1[1];
      const float z1f = zb[srow][cu * 4 + 2] + bz1[2];
      const float z1o = zb[srow][cu * 4 + 3] + bz1[3];
      const float nc = c1r * sigm(z1f + 1.0f) + sigm(z1i) * tanh_f(z1j);
      const float nh = tanh_f(nc) * sigm(z1o);
      c1r = nc;
      store_u16_llc(&hg1[(size_t)((p + 2) % 3) * HPS + srow * 1024 + fpos], f2h(nh));
      if (p - 1 == clen - 1) out[(size_t)cperm * 1024 + ug] = nh;
    }

    // ---- (G) global barrier: leaderless 256-flag poll (r12-proven) ----
    vm_wait0();                           // h stores LLC-visible
    __syncthreads();
    if (tid == 0) store_u32_llc((unsigned*)&ctr[F_ARR + bid], p + 1);
    if (tid < 256) {
      if (!spin_ge(&ctr[F_ARR + tid], p + 1)) s_ok = 0;
    }
    __syncthreads();
    if (!s_ok) break;
  }
}

// ======================= host launch =======================================

extern "C" void kernel_launch(void* const* d_in, const int* in_sizes, int n_in,
                              void* d_out, int out_size, void* d_ws, size_t ws_size,
                              hipStream_t stream) {
  const int*   ib   = (const int*)d_in[0];
  const int*   lens = (const int*)d_in[1];
  const float* emb  = (const float*)d_in[2];
  const float* W0   = (const float*)d_in[3];
  const float* b0   = (const float*)d_in[4];
  const float* W1   = (const float*)d_in[5];
  const float* b1   = (const float*)d_in[6];
  (void)in_sizes; (void)n_in; (void)out_size; (void)ws_size;

  char* ws = (char*)d_ws;
  size_t off = 0;
  auto alloc = [&](size_t bytes) { char* q = ws + off; off += (bytes + 255) & ~(size_t)255; return q; };

  int*            ctr  = (int*)alloc(8192);
  unsigned short* hg0  = (unsigned short*)alloc((size_t)3 * HPS * 2);
  unsigned short* hg1  = (unsigned short*)alloc((size_t)3 * HPS * 2);
  const size_t zero_bytes = off;          // ctr + h planes
  unsigned short* embF = (unsigned short*)alloc(128 * 256 * 2);
  int*            perm = (int*)alloc(4096);
  int*            lenS = perm + 128;
  int*            ncnt = perm + 256;
  unsigned short* rep  = (unsigned short*)alloc((size_t)8 * 2 * HPS * 2);
  uint4*          Whi0 = (uint4*)alloc((size_t)NBLK * KT0B * 64 * 16);
  uint4*          Whi1 = (uint4*)alloc((size_t)NBLK * KT1B * 64 * 16);

  hipMemsetAsync(d_ws, 0, zero_bytes, stream);
  prep_sort<<<1, 512, 0, stream>>>(lens, perm, lenS, ncnt);
  prep_emb<<<128, 256, 0, stream>>>(emb, embF);
  prep_wslab<<<(NBLK * KT0B * 64) / 256, 256, 0, stream>>>(W0, Whi0, KT0B);
  prep_wslab<<<(NBLK * KT1B * 64) / 256, 256, 0, stream>>>(W1, Whi1, KT1B);
  lstm_persist<<<NBLK, THREADS, 0, stream>>>(
      ib, b0, b1, Whi0, Whi1, embF,
      perm, lenS, ncnt, hg0, hg1, rep, ctr, (float*)d_out);
}

// Round 15
// 7468.180 us; speedup vs baseline: 2.4695x; 1.2177x over previous
//
#include <hip/hip_runtime.h>

// ---------------------------------------------------------------------------
// 2-layer LSTM encoder, B=128 T=512 E=256 H=1024 (round 15).
// Persistent kernel: 256 blocks x 512 threads (8 waves, fused dual-layer).
// Per phase p: L0 (t=p): z0=[x_p;h0(p-1)]@W0 -> h0(p)
//             L1 (t=p-1): z1=[h0(p-1);h1(p-2)]@W1 -> h1(p-1)
// NUMERICS (r13/r14-verified, absmax 2.44e-4): W fp16 LDS-resident (104 KB),
// h fp16 planes, 1 MFMA/kt (mfma_f32_16x16x32_f16), fp32 cell in registers.
// r15 (serial-spine + pipeline):
//  - TREE global barrier: arrive flag -> XCD leader polls 32 -> XDONE[xcd]
//    -> all poll <=8 XDONE. ~32x less LLC poll congestion.
//  - cell section: 1 __syncthreads (was 4) via zb[2] double buffer.
//  - GEMM body: explicit 2-deep x 8-frag A-prefetch double-buffer (static
//    indices) -> ~16 loads in flight/wave.
// Structure: per-XCD replica dist (overlapped with X-part GEMM), flat XCD
// barrier + inv_l1, length-sorted row gating, LLC (sc0 sc1) flags everywhere.
// ---------------------------------------------------------------------------

namespace {
constexpr int NBLK = 256, THREADS = 512;
constexpr int KT0B = 40;           // L0 k-tiles of 32 (K=1280): 8 X + 32 D
constexpr int KT1B = 64;           // L1 k-tiles of 32 (K=2048): 32 D + 32 H1
constexpr int NPH = 513;
constexpr int HPS = 128 * 1024;    // u16 elems per h plane (per layer)
constexpr int SPIN_CAP = 2000000;
// flag slots (u32 index into ctr[2048], zeroed per launch) — ALL LLC
constexpr int F_CREG  = 0;         // 8 x 16 (boot atomics)
constexpr int F_BOOT  = 128;
constexpr int F_GARR  = 256;       // 8 x 64 global-arrive per XCD
constexpr int F_XDONE = 768;       // 8 x 16 XCD-done
constexpr int F_XARR  = 1024;      // 8 x 64 mid-phase XCD arrive
}

typedef _Float16 f16x8 __attribute__((ext_vector_type(8)));
typedef float f32x4 __attribute__((ext_vector_type(4)));
typedef unsigned u32x4 __attribute__((ext_vector_type(4)));

__host__ __device__ __forceinline__ int fswz(int kk) {   // frag order within 32
  return ((kk & 15) >> 2) * 8 + (kk >> 4) * 4 + (kk & 3);
}

__device__ __forceinline__ float sigm(float x) { return 1.0f / (1.0f + __expf(-x)); }
__device__ __forceinline__ float tanh_f(float x) {
  float e = __expf(-2.0f * fabsf(x));
  float r = (1.0f - e) / (1.0f + e);
  return x >= 0.0f ? r : -r;
}
__device__ __forceinline__ unsigned short f2h(float f) {
  _Float16 h = (_Float16)f;
  return __builtin_bit_cast(unsigned short, h);
}

// ---- LLC-coherent ops (bypass L1+L2) --------------------------------------
__device__ __forceinline__ int load_i32_llc(const int* p) {
  int v;
  asm volatile("global_load_dword %0, %1, off sc0 sc1\n\ts_waitcnt vmcnt(0)"
               : "=v"(v) : "v"(p) : "memory");
  return v;
}
__device__ __forceinline__ uint4 llc_load_issue(const unsigned* p) {
  uint4 v;
  asm volatile("global_load_dwordx4 %0, %1, off sc0 sc1" : "=v"(v) : "v"(p));
  return v;
}
__device__ __forceinline__ void vm_wait0() {
  asm volatile("s_waitcnt vmcnt(0)" ::: "memory");
  __builtin_amdgcn_sched_barrier(0);
}
__device__ __forceinline__ void store_u32_llc(unsigned* p, unsigned v) {
  asm volatile("global_store_dword %0, %1, off sc0 sc1" :: "v"(p), "v"(v) : "memory");
}
__device__ __forceinline__ void store_u16_llc(unsigned short* p, unsigned short v) {
  asm volatile("global_store_short %0, %1, off sc0 sc1" :: "v"(p), "v"(v) : "memory");
}
__device__ __forceinline__ void inv_l1() {
  asm volatile("buffer_inv" ::: "memory");
}
__device__ __forceinline__ int xcc_id() {
  int x;
  asm("s_getreg_b32 %0, hwreg(HW_REG_XCC_ID)" : "=s"(x));
  return x & 7;
}
__device__ __forceinline__ int spin_ge(int* p, int target) {
  for (int it = 0; it < SPIN_CAP; ++it) {
    if (load_i32_llc(p) >= target) return 1;
    __builtin_amdgcn_s_sleep(1);
  }
  return 0;
}
__device__ __forceinline__ f16x8 ash(u32x4 v) { return __builtin_bit_cast(f16x8, v); }
__device__ __forceinline__ f16x8 ash4(uint4 v) { return __builtin_bit_cast(f16x8, v); }

#define MFMA1(acc, ah, bh)                                                    \
  acc = __builtin_amdgcn_mfma_f32_16x16x32_f16(ah, bh, acc, 0, 0, 0);

// ======================= prep kernels =====================================

__global__ void prep_sort(const int* __restrict__ lens, int* __restrict__ perm,
                          int* __restrict__ lenS, int* __restrict__ ncnt) {
  __shared__ int k_[128], p_[128];
  const int tid = threadIdx.x;
  if (tid < 128) { k_[tid] = (lens[tid] << 8) | (127 - tid); p_[tid] = tid; }
  __syncthreads();
  for (int ph = 0; ph < 128; ++ph) {
    if (tid < 64) {
      int a = 2 * tid + (ph & 1), b = a + 1;
      if (b < 128 && k_[a] < k_[b]) {
        int tk = k_[a]; k_[a] = k_[b]; k_[b] = tk;
        int tp = p_[a]; p_[a] = p_[b]; p_[b] = tp;
      }
    }
    __syncthreads();
  }
  if (tid < 128) { perm[tid] = p_[tid]; lenS[tid] = k_[tid] >> 8; }
  if (tid < 512) {
    int c = 0;
    for (int i = 0; i < 128; ++i) c += ((k_[i] >> 8) > tid) ? 1 : 0;
    ncnt[tid] = c;
  }
}

// emb -> single fp16 plane, fragment-interleaved order
__global__ void prep_emb(const float* __restrict__ emb,
                         unsigned short* __restrict__ ef) {
  int i = blockIdx.x * 256 + threadIdx.x;   // 32768
  int row = i >> 8, e = i & 255;
  int pos = row * 256 + (e >> 5) * 32 + fswz(e & 31);
  ef[pos] = f2h(emb[i]);
}

// W[k][4096] -> per-block fp16 frag slabs: e = (blk*KT + kt)*64 + lane.
__global__ void prep_wslab(const float* __restrict__ W, uint4* __restrict__ Whi,
                           int KT) {
  int e = blockIdx.x * 256 + threadIdx.x;
  int lane = e & 63;
  int kt = (e >> 6) % KT;
  int blk = e / (64 * KT);
  int cf = lane & 15;
  int g = cf & 3, ul = cf >> 2;
  int col = g * 1024 + blk * 4 + ul;
  int kbase = kt * 32 + ((lane >> 4) & 3) * 4;
  unsigned hi[8];
#pragma unroll
  for (int j = 0; j < 8; ++j) {
    int k = kbase + (j & 3) + 16 * (j >> 2);
    float f = W[(size_t)k * 4096 + col];
    hi[j] = __builtin_bit_cast(unsigned short, (_Float16)f);
  }
  uint4 vh;
  vh.x = hi[0] | (hi[1] << 16); vh.y = hi[2] | (hi[3] << 16);
  vh.z = hi[4] | (hi[5] << 16); vh.w = hi[6] | (hi[7] << 16);
  Whi[e] = vh;
}

// ======================= persistent kernel =================================

__global__ __launch_bounds__(THREADS, 1) void lstm_persist(
    const int* __restrict__ ib,
    const float* __restrict__ bias0, const float* __restrict__ bias1,
    const uint4* __restrict__ Whi0g, const uint4* __restrict__ Whi1g,
    const unsigned short* __restrict__ embF,
    const int* __restrict__ perm, const int* __restrict__ lenS,
    const int* __restrict__ ncnt,
    unsigned short* hg0, unsigned short* hg1,   // [3][128][1024] f16 frag-order
    unsigned short* rep,                        // [8][2][128][1024] f16
    int* ctr, float* __restrict__ out) {
  const int bid = blockIdx.x;
  const int tid = threadIdx.x;
  const int w = tid >> 6;                 // wave 0..7 -> rows w*16..+15
  const int lane = tid & 63;
  const int lr = lane & 15;
  const int lg4 = ((lane >> 4) & 3) * 4;
  const int slotE = ((lane >> 4) & 3) * 8;  // frag u16 offset within 32-group
  const int arow = w * 16 + lr;           // GEMM A row for this lane
  const int srow = tid >> 2;              // cell row 0..127
  const int cu = tid & 3;                 // cell unit 0..3
  const int ug = bid * 4 + cu;            // global unit
  const int fpos = (ug >> 5) * 32 + fswz(ug & 31);
  const int permA = perm[arow];
  const int cperm = perm[srow];
  const int clen = lenS[srow];

  __shared__ uint4 Wh0[KT0B * 64];              // 40 KB
  __shared__ uint4 Wh1[KT1B * 64];              // 64 KB
  __shared__ float zb[2][128][17];              // 17 KB (dbuf: L0, L1)
  __shared__ int s_x, s_rk, s_R, s_pres, s_ok;

  // ---- one-time: W fp16 slabs -> LDS (fully resident) ----
  {
    const uint4* s0 = Whi0g + (size_t)bid * (KT0B * 64);
    for (int i = tid; i < KT0B * 64; i += THREADS) Wh0[i] = s0[i];
    const uint4* s1 = Whi1g + (size_t)bid * (KT1B * 64);
    for (int i = tid; i < KT1B * 64; i += THREADS) Wh1[i] = s1[i];
  }

  float bz0[4], bz1[4];
#pragma unroll
  for (int g = 0; g < 4; ++g) {
    bz0[g] = bias0[g * 1024 + ug];
    bz1[g] = bias1[g * 1024 + ug];
  }
  float c0r = 0.0f, c1r = 0.0f;

  // ---- bootstrap (LLC atomics, once) ----
  if (tid == 0) {
    s_ok = 1;
    int x = xcc_id();
    s_x = x;
    s_rk = atomicAdd(&ctr[F_CREG + x * 16], 1);
    vm_wait0();
    atomicAdd(&ctr[F_BOOT], 1);
    if (!spin_ge(&ctr[F_BOOT], NBLK)) s_ok = 0;
    int Rv = 1, pres = 0;
    for (int i = 0; i < 8; ++i) {
      int r = load_i32_llc(&ctr[F_CREG + i * 16]);
      if (r > 0) pres |= (1 << i);
      if (i == s_x) Rv = r;
    }
    s_R = Rv;
    s_pres = pres;
  }
  __syncthreads();
  const int xcd = s_x, rk = s_rk, R = s_R, pres = s_pres;
  if (!s_ok) return;

  unsigned short* repB = rep + (size_t)xcd * 2 * HPS;
  const unsigned short* A0 = repB + (size_t)arow * 1024;          // h0 plane
  const unsigned short* A1 = repB + HPS + (size_t)arow * 1024;    // h1 plane

  // distribution role: plane pl (0=h0,1=h1), row-offset bit, 16B chunk
  const int pl = tid >> 8;                // 0..1
  const int rowoff = (tid >> 7) & 1;      // row pair bit
  const int ch = (tid & 127) * 8;         // u16 offset in row
  unsigned short* dp = repB + pl * HPS;

  for (int p = 0; p < NPH; ++p) {
    const int nact0 = (p < 512) ? ncnt[p] : 0;
    const int nact1 = (p >= 1) ? ncnt[p - 1] : 0;
    const bool doL0 = (p < 512) && (w * 16 < nact0);
    const bool doL1 = (p >= 1) && (w * 16 < nact1);
    const int ncopy = ncnt[p == 0 ? 0 : p - 1];

    f32x4 acc0 = (f32x4){0.f, 0.f, 0.f, 0.f};
    f32x4 acc1 = (f32x4){0.f, 0.f, 0.f, 0.f};

    // ---- (A) dist: ISSUE LLC loads (h0(p-1) / h1(p-2) planes) ----
    const unsigned short* sp =
        (pl == 0) ? (hg0 + (size_t)((p + 2) % 3) * HPS)
                  : (hg1 + (size_t)((p + 1) % 3) * HPS);
    const int step = 2 * R;
    const int dr0 = 2 * rk + rowoff;
    const int dr1 = dr0 + step, dr2 = dr0 + 2 * step, dr3 = dr0 + 3 * step;
    uint4 dv0, dv1, dv2, dv3;
    if (dr0 < ncopy) dv0 = llc_load_issue((const unsigned*)(sp + dr0 * 1024 + ch));
    if (dr1 < ncopy) dv1 = llc_load_issue((const unsigned*)(sp + dr1 * 1024 + ch));
    if (dr2 < ncopy) dv2 = llc_load_issue((const unsigned*)(sp + dr2 * 1024 + ch));
    if (dr3 < ncopy) dv3 = llc_load_issue((const unsigned*)(sp + dr3 * 1024 + ch));

    // ---- (B) X-part GEMM (emb + LDS W0; overlaps dist latency) ----
    if (doL0) {
      const int tok = ib[(size_t)permA * 512 + p];
      const unsigned short* ef = embF + tok * 256;
#pragma unroll
      for (int kt = 0; kt < 8; ++kt) {
        const f16x8 ah = ash(*(const u32x4*)(ef + kt * 32 + slotE));
        MFMA1(acc0, ah, ash4(Wh0[kt * 64 + lane]))
      }
    }

    // ---- (C) finish dist: wait + store into replica (plain L2 stores) ----
    vm_wait0();
    if (dr0 < ncopy) *(uint4*)(dp + dr0 * 1024 + ch) = dv0;
    if (dr1 < ncopy) *(uint4*)(dp + dr1 * 1024 + ch) = dv1;
    if (dr2 < ncopy) *(uint4*)(dp + dr2 * 1024 + ch) = dv2;
    if (dr3 < ncopy) *(uint4*)(dp + dr3 * 1024 + ch) = dv3;
    for (int r = dr0 + 4 * step; r < ncopy; r += step) {
      uint4 v = llc_load_issue((const unsigned*)(sp + r * 1024 + ch));
      vm_wait0();
      *(uint4*)(dp + r * 1024 + ch) = v;
    }
    __syncthreads();                      // dist stores drained (vmcnt(0))

    // ---- (D) XCD barrier (flat LLC flags) + L1 inv ----
    if (tid == 0) store_u32_llc((unsigned*)&ctr[F_XARR + xcd * 64 + rk], p + 1);
    if (tid < 64 && tid < R) {
      if (!spin_ge(&ctr[F_XARR + xcd * 64 + tid], p + 1)) s_ok = 0;
    }
    __syncthreads();
    if (!s_ok) break;
    inv_l1();                             // fresh L1 view of replica

    // ---- (E) main GEMM: 2-deep x 8-frag A-prefetch pipeline ----
    if (doL0 || doL1) {
      u32x4 a[2][8];
#pragma unroll
      for (int i = 0; i < 8; ++i) a[0][i] = *(const u32x4*)(A0 + i * 32 + slotE);
      // A0 region: groups g=0..3 (q = g*8+i), prefetch next group
#pragma unroll
      for (int g = 0; g < 4; ++g) {
        const int cb = g & 1;
        if (g < 3) {
#pragma unroll
          for (int i = 0; i < 8; ++i)
            a[cb ^ 1][i] = *(const u32x4*)(A0 + ((g + 1) * 8 + i) * 32 + slotE);
        } else if (doL1) {
#pragma unroll
          for (int i = 0; i < 8; ++i)
            a[cb ^ 1][i] = *(const u32x4*)(A1 + i * 32 + slotE);
        }
#pragma unroll
        for (int i = 0; i < 8; ++i) {
          const int q = g * 8 + i;
          const f16x8 ah = ash(a[cb][i]);
          if (doL0) { MFMA1(acc0, ah, ash4(Wh0[(8 + q) * 64 + lane])) }
          if (doL1) { MFMA1(acc1, ah, ash4(Wh1[q * 64 + lane])) }
        }
      }
      // A1 region: groups g=0..3 (parity continues: group 0 sits in buf 0)
      if (doL1) {
#pragma unroll
        for (int g = 0; g < 4; ++g) {
          const int cb = g & 1;
          if (g < 3) {
#pragma unroll
            for (int i = 0; i < 8; ++i)
              a[cb ^ 1][i] = *(const u32x4*)(A1 + ((g + 1) * 8 + i) * 32 + slotE);
          }
#pragma unroll
          for (int i = 0; i < 8; ++i) {
            const int q = g * 8 + i;
            const f16x8 ah = ash(a[cb][i]);
            MFMA1(acc1, ah, ash4(Wh1[(32 + q) * 64 + lane]))
          }
        }
      }
    }

    // ---- (F) z exchange (zb dbuf, ONE sync) + cells ----
    if (doL0) {
#pragma unroll
      for (int rr = 0; rr < 4; ++rr) zb[0][w * 16 + lg4 + rr][lr] = acc0[rr];
    }
    if (doL1) {
#pragma unroll
      for (int rr = 0; rr < 4; ++rr) zb[1][w * 16 + lg4 + rr][lr] = acc1[rr];
    }
    __syncthreads();
    if (p < 512 && p < clen) {            // L0 cell, t = p
      const float zi = zb[0][srow][cu * 4 + 0] + bz0[0];
      const float zj = zb[0][srow][cu * 4 + 1] + bz0[1];
      const float zf = zb[0][srow][cu * 4 + 2] + bz0[2];
      const float zo = zb[0][srow][cu * 4 + 3] + bz0[3];
      const float nc = c0r * sigm(zf + 1.0f) + sigm(zi) * tanh_f(zj);
      const float nh = tanh_f(nc) * sigm(zo);
      c0r = nc;
      store_u16_llc(&hg0[(size_t)(p % 3) * HPS + srow * 1024 + fpos], f2h(nh));
    }
    if (p >= 1 && (p - 1) < clen) {       // L1 cell, t = p-1
      const float zi = zb[1][srow][cu * 4 + 0] + bz1[0];
      const float zj = zb[1][srow][cu * 4 + 1] + bz1[1];
      const float zf = zb[1][srow][cu * 4 + 2] + bz1[2];
      const float zo = zb[1][srow][cu * 4 + 3] + bz1[3];
      const float nc = c1r * sigm(zf + 1.0f) + sigm(zi) * tanh_f(zj);
      const float nh = tanh_f(nc) * sigm(zo);
      c1r = nc;
      store_u16_llc(&hg1[(size_t)((p + 2) % 3) * HPS + srow * 1024 + fpos], f2h(nh));
      if (p - 1 == clen - 1) out[(size_t)cperm * 1024 + ug] = nh;
    }

    // ---- (G) TREE global barrier (low poll traffic) ----
    vm_wait0();                           // h stores LLC-visible
    __syncthreads();
    if (tid == 0) store_u32_llc((unsigned*)&ctr[F_GARR + xcd * 64 + rk], p + 1);
    if (rk == 0) {                        // XCD leader block
      if (tid < 64 && tid < R) {
        if (!spin_ge(&ctr[F_GARR + xcd * 64 + tid], p + 1)) s_ok = 0;
      }
      __syncthreads();
      if (tid == 0) store_u32_llc((unsigned*)&ctr[F_XDONE + xcd * 16], p + 1);
    }
    if (tid < 8 && ((pres >> tid) & 1)) {
      if (!spin_ge(&ctr[F_XDONE + tid * 16], p + 1)) s_ok = 0;
    }
    __syncthreads();
    if (!s_ok) break;
  }
}

// ======================= host launch =======================================

extern "C" void kernel_launch(void* const* d_in, const int* in_sizes, int n_in,
                              void* d_out, int out_size, void* d_ws, size_t ws_size,
                              hipStream_t stream) {
  const int*   ib   = (const int*)d_in[0];
  const int*   lens = (const int*)d_in[1];
  const float* emb  = (const float*)d_in[2];
  const float* W0   = (const float*)d_in[3];
  const float* b0   = (const float*)d_in[4];
  const float* W1   = (const float*)d_in[5];
  const float* b1   = (const float*)d_in[6];
  (void)in_sizes; (void)n_in; (void)out_size; (void)ws_size;

  char* ws = (char*)d_ws;
  size_t off = 0;
  auto alloc = [&](size_t bytes) { char* q = ws + off; off += (bytes + 255) & ~(size_t)255; return q; };

  int*            ctr  = (int*)alloc(8192);
  unsigned short* hg0  = (unsigned short*)alloc((size_t)3 * HPS * 2);
  unsigned short* hg1  = (unsigned short*)alloc((size_t)3 * HPS * 2);
  const size_t zero_bytes = off;          // ctr + h planes
  unsigned short* embF = (unsigned short*)alloc(128 * 256 * 2);
  int*            perm = (int*)alloc(4096);
  int*            lenS = perm + 128;
  int*            ncnt = perm + 256;
  unsigned short* rep  = (unsigned short*)alloc((size_t)8 * 2 * HPS * 2);
  uint4*          Whi0 = (uint4*)alloc((size_t)NBLK * KT0B * 64 * 16);
  uint4*          Whi1 = (uint4*)alloc((size_t)NBLK * KT1B * 64 * 16);

  hipMemsetAsync(d_ws, 0, zero_bytes, stream);
  prep_sort<<<1, 512, 0, stream>>>(lens, perm, lenS, ncnt);
  prep_emb<<<128, 256, 0, stream>>>(emb, embF);
  prep_wslab<<<(NBLK * KT0B * 64) / 256, 256, 0, stream>>>(W0, Whi0, KT0B);
  prep_wslab<<<(NBLK * KT1B * 64) / 256, 256, 0, stream>>>(W1, Whi1, KT1B);
  lstm_persist<<<NBLK, THREADS, 0, stream>>>(
      ib, b0, b1, Whi0, Whi1, embF,
      perm, lenS, ncnt, hg0, hg1, rep, ctr, (float*)d_out);
}